// Round 1
// baseline (405.480 us; speedup 1.0000x reference)
//
#include <hip/hip_runtime.h>
#include <hip/hip_bf16.h>
#include <math.h>

typedef __bf16 bf16;
typedef __attribute__((ext_vector_type(8))) __bf16 bf16x8;
typedef __attribute__((ext_vector_type(4))) float f32x4;

#define DEV static __device__ __forceinline__

typedef const void __attribute__((address_space(1)))* gptr_t;
typedef void __attribute__((address_space(3)))* lptr_t;

DEV void async16(const void* g, void* l) {
  __builtin_amdgcn_global_load_lds((gptr_t)g, (lptr_t)l, 16, 0, 0);
}

// ---------------- fp32 -> bf16 convert (weights) ----------------
__global__ __launch_bounds__(256) void f2b_kernel(const float* __restrict__ in,
                                                  bf16* __restrict__ out, int n) {
  int i = (blockIdx.x * 256 + threadIdx.x) * 4;
  if (i + 3 < n) {
    float4 v = *(const float4*)(in + i);
    out[i + 0] = (bf16)v.x;
    out[i + 1] = (bf16)v.y;
    out[i + 2] = (bf16)v.z;
    out[i + 3] = (bf16)v.w;
  }
}

// ---------------- LayerNorm: fp32 in -> bf16 out, row = 1024 ----------------
__global__ __launch_bounds__(256) void ln_kernel(const float* __restrict__ in,
                                                 const float* __restrict__ g,
                                                 const float* __restrict__ b,
                                                 bf16* __restrict__ out) {
  const int row = blockIdx.x;
  const int tid = threadIdx.x;
  float4 v = ((const float4*)(in + (size_t)row * 1024))[tid];
  float s = v.x + v.y + v.z + v.w;
  float s2 = v.x * v.x + v.y * v.y + v.z * v.z + v.w * v.w;
#pragma unroll
  for (int off = 1; off < 64; off <<= 1) {
    s += __shfl_xor(s, off);
    s2 += __shfl_xor(s2, off);
  }
  __shared__ float red[8];
  int w = tid >> 6, lane = tid & 63;
  if (lane == 0) { red[w] = s; red[4 + w] = s2; }
  __syncthreads();
  s = red[0] + red[1] + red[2] + red[3];
  s2 = red[4] + red[5] + red[6] + red[7];
  const float mean = s * (1.f / 1024.f);
  const float var = s2 * (1.f / 1024.f) - mean * mean;
  const float rstd = rsqrtf(var + 1e-5f);
  float4 gv = ((const float4*)g)[tid];
  float4 bv = ((const float4*)b)[tid];
  bf16* orow = out + (size_t)row * 1024 + tid * 4;
  orow[0] = (bf16)((v.x - mean) * rstd * gv.x + bv.x);
  orow[1] = (bf16)((v.y - mean) * rstd * gv.y + bv.y);
  orow[2] = (bf16)((v.z - mean) * rstd * gv.z + bv.z);
  orow[3] = (bf16)((v.w - mean) * rstd * gv.w + bv.w);
}

// ---------------- GEMM: C[M,N] = A[M,K] * B[N,K]^T  (+epilogue) ----------------
// EPI 0: out bf16, no bias. EPI 1: bias + exact GELU -> bf16. EPI 2: bias + resid -> fp32.
template <int EPI>
__global__ __launch_bounds__(256, 2) void gemm_bt(const bf16* __restrict__ A,
                                                  const bf16* __restrict__ B,
                                                  bf16* __restrict__ outb,
                                                  float* __restrict__ outf,
                                                  const float* __restrict__ bias,
                                                  const float* __restrict__ resid,
                                                  int M, int N, int K) {
  __shared__ bf16 As[128 * 64];
  __shared__ bf16 Bs[128 * 64];
  const int tid = threadIdx.x;
  const int lane = tid & 63, w = tid >> 6;
  const int lr = lane & 15, lk = (lane >> 4) * 8;
  const int wr = (w >> 1) * 64, wc = (w & 1) * 64;
  const int brow = blockIdx.y * 128, bcol = blockIdx.x * 128;
  const int sr = tid >> 3, sc = (tid & 7) * 8;
  f32x4 acc[4][4] = {};
  const bf16* Ab = A + (size_t)(brow + sr) * K + sc;
  const bf16* Bb = B + (size_t)(bcol + sr) * K + sc;
  for (int k0 = 0; k0 < K; k0 += 64) {
#pragma unroll
    for (int i = 0; i < 4; ++i) {
      async16(Ab + (size_t)(i * 32) * K + k0, &As[(i * 32 + sr) * 64 + sc]);
      async16(Bb + (size_t)(i * 32) * K + k0, &Bs[(i * 32 + sr) * 64 + sc]);
    }
    __syncthreads();
#pragma unroll
    for (int kk = 0; kk < 2; ++kk) {
      bf16x8 af[4], bfr[4];
#pragma unroll
      for (int m = 0; m < 4; ++m)
        af[m] = *(const bf16x8*)&As[(wr + m * 16 + lr) * 64 + kk * 32 + lk];
#pragma unroll
      for (int n = 0; n < 4; ++n)
        bfr[n] = *(const bf16x8*)&Bs[(wc + n * 16 + lr) * 64 + kk * 32 + lk];
#pragma unroll
      for (int m = 0; m < 4; ++m)
#pragma unroll
        for (int n = 0; n < 4; ++n)
          acc[m][n] = __builtin_amdgcn_mfma_f32_16x16x32_bf16(af[m], bfr[n], acc[m][n], 0, 0, 0);
    }
    __syncthreads();
  }
  const int r0 = brow + wr + (lane >> 4) * 4;
  const int c0 = bcol + wc + lr;
#pragma unroll
  for (int m = 0; m < 4; ++m)
#pragma unroll
    for (int n = 0; n < 4; ++n)
#pragma unroll
      for (int j = 0; j < 4; ++j) {
        const int r = r0 + m * 16 + j;
        const int c = c0 + n * 16;
        float v = acc[m][n][j];
        if (EPI == 0) {
          outb[(size_t)r * N + c] = (bf16)v;
        } else if (EPI == 1) {
          v += bias[c];
          v = 0.5f * v * (1.0f + erff(v * 0.70710678118654752f));
          outb[(size_t)r * N + c] = (bf16)v;
        } else {
          v += bias[c] + resid[(size_t)r * N + c];
          outf[(size_t)r * N + c] = v;
        }
      }
}

// ---------------- Flash attention ----------------
// qkv: [4096, 3072] bf16, row = b*2048+n, col = which*1024 + h*64 + d
// out: [4096, 1024] bf16 (head-concat)
__global__ __launch_bounds__(256, 4) void flash_kernel(const bf16* __restrict__ qkv,
                                                       bf16* __restrict__ out) {
  const int qt = blockIdx.x;       // 0..31 (q tile of 64)
  const int bh = blockIdx.y;       // 0..31
  const int b = bh >> 4, h = bh & 15;
  const int tid = threadIdx.x;
  const int lane = tid & 63, w = tid >> 6;
  const int lr = lane & 15, lk4 = lane >> 4;
  const bf16* Qp = qkv + (size_t)(b * 2048) * 3072 + h * 64;
  const bf16* Kp = Qp + 1024;
  const bf16* Vp = Qp + 2048;
  __shared__ bf16 Ks[64 * 64];
  __shared__ bf16 VTs[64 * 64];
  __shared__ bf16 Ps[64 * 64];
  const int q0 = qt * 64 + w * 16;
  bf16x8 qf[2];
#pragma unroll
  for (int kk = 0; kk < 2; ++kk)
    qf[kk] = *(const bf16x8*)(Qp + (size_t)(q0 + lr) * 3072 + kk * 32 + lk4 * 8);
  f32x4 o[4] = {};
  float mrun[4] = {-1e30f, -1e30f, -1e30f, -1e30f};
  float lrun[4] = {0.f, 0.f, 0.f, 0.f};
  const int sr = tid >> 3, sc = (tid & 7) * 8;
  const int vkv = tid >> 2, vd = (tid & 3) * 16;
  for (int t = 0; t < 32; ++t) {
    const int kv0 = t * 64;
    // stage K tile (64x64) via global_load_lds
#pragma unroll
    for (int i = 0; i < 2; ++i)
      async16(Kp + (size_t)(kv0 + i * 32 + sr) * 3072 + sc, &Ks[(i * 32 + sr) * 64 + sc]);
    // stage V^T via registers
    {
      const bf16* Vrow = Vp + (size_t)(kv0 + vkv) * 3072;
      bf16x8 v0 = *(const bf16x8*)(Vrow + vd);
      bf16x8 v1 = *(const bf16x8*)(Vrow + vd + 8);
#pragma unroll
      for (int j = 0; j < 8; ++j) {
        VTs[(vd + j) * 64 + vkv] = v0[j];
        VTs[(vd + 8 + j) * 64 + vkv] = v1[j];
      }
    }
    __syncthreads();
    // S = Q K^T * scale
    f32x4 s[4] = {};
#pragma unroll
    for (int n = 0; n < 4; ++n) {
#pragma unroll
      for (int kk = 0; kk < 2; ++kk) {
        bf16x8 kf = *(const bf16x8*)&Ks[(n * 16 + lr) * 64 + kk * 32 + lk4 * 8];
        s[n] = __builtin_amdgcn_mfma_f32_16x16x32_bf16(qf[kk], kf, s[n], 0, 0, 0);
      }
#pragma unroll
      for (int j = 0; j < 4; ++j) s[n][j] *= 0.125f;
    }
    // online softmax (rows live in 16-lane groups)
    float ps[4][4];
#pragma unroll
    for (int j = 0; j < 4; ++j) {
      float mx = -1e30f;
#pragma unroll
      for (int n = 0; n < 4; ++n) mx = fmaxf(mx, s[n][j]);
#pragma unroll
      for (int off = 8; off; off >>= 1) mx = fmaxf(mx, __shfl_xor(mx, off));
      const float mn = fmaxf(mrun[j], mx);
      const float alpha = __expf(mrun[j] - mn);
      mrun[j] = mn;
      float rs = 0.f;
#pragma unroll
      for (int n = 0; n < 4; ++n) {
        float p = __expf(s[n][j] - mn);
        ps[n][j] = p;
        rs += p;
      }
#pragma unroll
      for (int off = 8; off; off >>= 1) rs += __shfl_xor(rs, off);
      lrun[j] = lrun[j] * alpha + rs;
#pragma unroll
      for (int c = 0; c < 4; ++c) o[c][j] *= alpha;
    }
    // P -> LDS (wave-local rows)
#pragma unroll
    for (int n = 0; n < 4; ++n)
#pragma unroll
      for (int j = 0; j < 4; ++j)
        Ps[(w * 16 + lk4 * 4 + j) * 64 + n * 16 + lr] = (bf16)ps[n][j];
    // PV
    bf16x8 pa[2];
#pragma unroll
    for (int kk = 0; kk < 2; ++kk)
      pa[kk] = *(const bf16x8*)&Ps[(w * 16 + lr) * 64 + kk * 32 + lk4 * 8];
#pragma unroll
    for (int c = 0; c < 4; ++c)
#pragma unroll
      for (int kk = 0; kk < 2; ++kk) {
        bf16x8 vf = *(const bf16x8*)&VTs[(c * 16 + lr) * 64 + kk * 32 + lk4 * 8];
        o[c] = __builtin_amdgcn_mfma_f32_16x16x32_bf16(pa[kk], vf, o[c], 0, 0, 0);
      }
    __syncthreads();
  }
  float inv[4];
#pragma unroll
  for (int j = 0; j < 4; ++j) inv[j] = 1.f / lrun[j];
#pragma unroll
  for (int c = 0; c < 4; ++c)
#pragma unroll
    for (int j = 0; j < 4; ++j)
      out[(size_t)(b * 2048 + q0 + lk4 * 4 + j) * 1024 + h * 64 + c * 16 + lr] =
          (bf16)(o[c][j] * inv[j]);
}

// ---------------- launch ----------------
extern "C" void kernel_launch(void* const* d_in, const int* in_sizes, int n_in,
                              void* d_out, int out_size, void* d_ws, size_t ws_size,
                              hipStream_t stream) {
  const float* x      = (const float*)d_in[0];
  const float* w_qkv  = (const float*)d_in[1];
  const float* w_proj = (const float*)d_in[2];
  const float* b_proj = (const float*)d_in[3];
  const float* ln1_g  = (const float*)d_in[4];
  const float* ln1_b  = (const float*)d_in[5];
  const float* ln2_g  = (const float*)d_in[6];
  const float* ln2_b  = (const float*)d_in[7];
  const float* w_fc1  = (const float*)d_in[8];
  const float* b_fc1  = (const float*)d_in[9];
  const float* w_fc2  = (const float*)d_in[10];
  const float* b_fc2  = (const float*)d_in[11];

  char* W = (char*)d_ws;
  bf16* wqkvb = (bf16*)(W + 0);                    //  6,291,456
  bf16* wprojb = (bf16*)(W + 6291456);             //  2,097,152
  bf16* wfc1b = (bf16*)(W + 8388608);              //  8,388,608
  bf16* wfc2b = (bf16*)(W + 16777216);             //  8,388,608
  bf16* xn    = (bf16*)(W + 25165824);             //  8,388,608
  bf16* qkvb  = (bf16*)(W + 33554432);             // 25,165,824
  bf16* attnb = (bf16*)(W + 58720256);             //  8,388,608
  float* x2   = (float*)(W + 67108864);            // 16,777,216
  bf16* hbuf  = (bf16*)(W + 83886080);             // 33,554,432
  float* outf = (float*)d_out;

  // weight conversions
  f2b_kernel<<<3072, 256, 0, stream>>>(w_qkv, wqkvb, 3145728);
  f2b_kernel<<<1024, 256, 0, stream>>>(w_proj, wprojb, 1048576);
  f2b_kernel<<<4096, 256, 0, stream>>>(w_fc1, wfc1b, 4194304);
  f2b_kernel<<<4096, 256, 0, stream>>>(w_fc2, wfc2b, 4194304);

  // LN1
  ln_kernel<<<4096, 256, 0, stream>>>(x, ln1_g, ln1_b, xn);
  // QKV GEMM: [4096,3072]
  gemm_bt<0><<<dim3(24, 32), 256, 0, stream>>>(xn, wqkvb, qkvb, nullptr, nullptr, nullptr,
                                               4096, 3072, 1024);
  // attention
  flash_kernel<<<dim3(32, 32), 256, 0, stream>>>(qkvb, attnb);
  // proj + bias + residual -> x2 (fp32)
  gemm_bt<2><<<dim3(8, 32), 256, 0, stream>>>(attnb, wprojb, nullptr, x2, b_proj, x,
                                              4096, 1024, 1024);
  // LN2
  ln_kernel<<<4096, 256, 0, stream>>>(x2, ln2_g, ln2_b, xn);
  // FC1 + bias + GELU
  gemm_bt<1><<<dim3(32, 32), 256, 0, stream>>>(xn, wfc1b, hbuf, nullptr, b_fc1, nullptr,
                                               4096, 4096, 1024);
  // FC2 + bias + residual -> out (fp32)
  gemm_bt<2><<<dim3(8, 32), 256, 0, stream>>>(hbuf, wfc2b, nullptr, outf, b_fc2, x2,
                                              4096, 1024, 4096);
}

// Round 2
// 342.680 us; speedup vs baseline: 1.1833x; 1.1833x over previous
//
#include <hip/hip_runtime.h>
#include <hip/hip_bf16.h>
#include <math.h>

typedef __bf16 bf16;
typedef __attribute__((ext_vector_type(8))) __bf16 bf16x8;
typedef __attribute__((ext_vector_type(4))) float f32x4;

#define DEV static __device__ __forceinline__

typedef const void __attribute__((address_space(1)))* gptr_t;
typedef void __attribute__((address_space(3)))* lptr_t;

DEV void async16(const void* g, void* l) {
  __builtin_amdgcn_global_load_lds((gptr_t)g, (lptr_t)l, 16, 0, 0);
}

// ---------------- fp32 -> bf16 convert (weights) ----------------
__global__ __launch_bounds__(256) void f2b_kernel(const float* __restrict__ in,
                                                  bf16* __restrict__ out, int n) {
  int i = (blockIdx.x * 256 + threadIdx.x) * 4;
  if (i + 3 < n) {
    float4 v = *(const float4*)(in + i);
    out[i + 0] = (bf16)v.x;
    out[i + 1] = (bf16)v.y;
    out[i + 2] = (bf16)v.z;
    out[i + 3] = (bf16)v.w;
  }
}

// ---------------- LayerNorm: fp32 in -> bf16 out, row = 1024 ----------------
__global__ __launch_bounds__(256) void ln_kernel(const float* __restrict__ in,
                                                 const float* __restrict__ g,
                                                 const float* __restrict__ b,
                                                 bf16* __restrict__ out) {
  const int row = blockIdx.x;
  const int tid = threadIdx.x;
  float4 v = ((const float4*)(in + (size_t)row * 1024))[tid];
  float s = v.x + v.y + v.z + v.w;
  float s2 = v.x * v.x + v.y * v.y + v.z * v.z + v.w * v.w;
#pragma unroll
  for (int off = 1; off < 64; off <<= 1) {
    s += __shfl_xor(s, off);
    s2 += __shfl_xor(s2, off);
  }
  __shared__ float red[8];
  int w = tid >> 6, lane = tid & 63;
  if (lane == 0) { red[w] = s; red[4 + w] = s2; }
  __syncthreads();
  s = red[0] + red[1] + red[2] + red[3];
  s2 = red[4] + red[5] + red[6] + red[7];
  const float mean = s * (1.f / 1024.f);
  const float var = s2 * (1.f / 1024.f) - mean * mean;
  const float rstd = rsqrtf(var + 1e-5f);
  float4 gv = ((const float4*)g)[tid];
  float4 bv = ((const float4*)b)[tid];
  bf16* orow = out + (size_t)row * 1024 + tid * 4;
  orow[0] = (bf16)((v.x - mean) * rstd * gv.x + bv.x);
  orow[1] = (bf16)((v.y - mean) * rstd * gv.y + bv.y);
  orow[2] = (bf16)((v.z - mean) * rstd * gv.z + bv.z);
  orow[3] = (bf16)((v.w - mean) * rstd * gv.w + bv.w);
}

// ---------------- GEMM: C[M,N] = A[M,K] * B[N,K]^T  (+epilogue) ----------------
template <int EPI>
__global__ __launch_bounds__(256, 2) void gemm_bt(const bf16* __restrict__ A,
                                                  const bf16* __restrict__ B,
                                                  bf16* __restrict__ outb,
                                                  float* __restrict__ outf,
                                                  const float* __restrict__ bias,
                                                  const float* __restrict__ resid,
                                                  int M, int N, int K) {
  __shared__ bf16 As[128 * 64];
  __shared__ bf16 Bs[128 * 64];
  const int tid = threadIdx.x;
  const int lane = tid & 63, w = tid >> 6;
  const int lr = lane & 15, lk = (lane >> 4) * 8;
  const int wr = (w >> 1) * 64, wc = (w & 1) * 64;
  const int brow = blockIdx.y * 128, bcol = blockIdx.x * 128;
  const int sr = tid >> 3, sc = (tid & 7) * 8;
  f32x4 acc[4][4] = {};
  const bf16* Ab = A + (size_t)(brow + sr) * K + sc;
  const bf16* Bb = B + (size_t)(bcol + sr) * K + sc;
  for (int k0 = 0; k0 < K; k0 += 64) {
#pragma unroll
    for (int i = 0; i < 4; ++i) {
      async16(Ab + (size_t)(i * 32) * K + k0, &As[(i * 32 + sr) * 64 + sc]);
      async16(Bb + (size_t)(i * 32) * K + k0, &Bs[(i * 32 + sr) * 64 + sc]);
    }
    __syncthreads();
#pragma unroll
    for (int kk = 0; kk < 2; ++kk) {
      bf16x8 af[4], bfr[4];
#pragma unroll
      for (int m = 0; m < 4; ++m)
        af[m] = *(const bf16x8*)&As[(wr + m * 16 + lr) * 64 + kk * 32 + lk];
#pragma unroll
      for (int n = 0; n < 4; ++n)
        bfr[n] = *(const bf16x8*)&Bs[(wc + n * 16 + lr) * 64 + kk * 32 + lk];
#pragma unroll
      for (int m = 0; m < 4; ++m)
#pragma unroll
        for (int n = 0; n < 4; ++n)
          acc[m][n] = __builtin_amdgcn_mfma_f32_16x16x32_bf16(af[m], bfr[n], acc[m][n], 0, 0, 0);
    }
    __syncthreads();
  }
  const int r0 = brow + wr + (lane >> 4) * 4;
  const int c0 = bcol + wc + lr;
#pragma unroll
  for (int m = 0; m < 4; ++m)
#pragma unroll
    for (int n = 0; n < 4; ++n)
#pragma unroll
      for (int j = 0; j < 4; ++j) {
        const int r = r0 + m * 16 + j;
        const int c = c0 + n * 16;
        float v = acc[m][n][j];
        if (EPI == 0) {
          outb[(size_t)r * N + c] = (bf16)v;
        } else if (EPI == 1) {
          v += bias[c];
          v = 0.5f * v * (1.0f + erff(v * 0.70710678118654752f));
          outb[(size_t)r * N + c] = (bf16)v;
        } else {
          v += bias[c] + resid[(size_t)r * N + c];
          outf[(size_t)r * N + c] = v;
        }
      }
}

// ---------------- Flash attention (swizzled LDS) ----------------
// qkv: [4096, 3072] bf16, row = b*2048+n, col = which*1024 + h*64 + d
// out: [4096, 1024] bf16 (head-concat)
// All LDS tiles are [row][64 bf16] with 16B-chunk XOR swizzle: chunk ^= (row&7).
__global__ __launch_bounds__(256, 4) void flash_kernel(const bf16* __restrict__ qkv,
                                                       bf16* __restrict__ out) {
  const int qt = blockIdx.x;       // 0..31 (q tile of 64)
  const int bh = blockIdx.y;       // 0..31
  const int b = bh >> 4, h = bh & 15;
  const int tid = threadIdx.x;
  const int lane = tid & 63, w = tid >> 6;
  const int lr = lane & 15, lk4 = lane >> 4;
  const bf16* Qp = qkv + (size_t)(b * 2048) * 3072 + h * 64;
  const bf16* Kp = Qp + 1024;
  const bf16* Vp = Qp + 2048;
  __shared__ bf16 Ks[64 * 64];
  __shared__ bf16 VTs[64 * 64];
  __shared__ bf16 Ps[64 * 64];
  const int q0 = qt * 64 + w * 16;
  bf16x8 qf[2];
#pragma unroll
  for (int kk = 0; kk < 2; ++kk)
    qf[kk] = *(const bf16x8*)(Qp + (size_t)(q0 + lr) * 3072 + kk * 32 + lk4 * 8);
  f32x4 o[4] = {};
  float mrun[4] = {-1e30f, -1e30f, -1e30f, -1e30f};
  float lrun[4] = {0.f, 0.f, 0.f, 0.f};
  const int sr = tid >> 3, sc8 = tid & 7;       // K staging: row-in-half, chunk
  const int vd = tid & 63, vkc = (tid >> 6) * 16;  // V transpose: d row, kv chunk base
  const int vc0 = vkc >> 3;                        // first 16B chunk (0,2,4,6)
  for (int t = 0; t < 32; ++t) {
    const int kv0 = t * 64;
    // ---- stage K tile (64x64) via global_load_lds, pre-swizzled source ----
#pragma unroll
    for (int i = 0; i < 2; ++i) {
      const int r = i * 32 + sr;
      async16(Kp + (size_t)(kv0 + r) * 3072 + (sc8 ^ (r & 7)) * 8,
              &Ks[r * 64 + sc8 * 8]);
    }
    // ---- gather V^T row-segment: 16 warp-coalesced 2B loads ----
    bf16 vv[16];
#pragma unroll
    for (int j = 0; j < 16; ++j)
      vv[j] = Vp[(size_t)(kv0 + vkc + j) * 3072 + vd];
    {
      bf16x8 a, c;
#pragma unroll
      for (int j = 0; j < 8; ++j) { a[j] = vv[j]; c[j] = vv[8 + j]; }
      *(bf16x8*)&VTs[vd * 64 + ((vc0 ^ (vd & 7)) * 8)] = a;
      *(bf16x8*)&VTs[vd * 64 + (((vc0 + 1) ^ (vd & 7)) * 8)] = c;
    }
    __syncthreads();
    // ---- S = Q K^T * scale ----
    f32x4 s[4] = {};
    __builtin_amdgcn_s_setprio(1);
#pragma unroll
    for (int n = 0; n < 4; ++n) {
#pragma unroll
      for (int kk = 0; kk < 2; ++kk) {
        bf16x8 kf = *(const bf16x8*)&Ks[(n * 16 + lr) * 64 + (((kk * 4 + lk4) ^ (lr & 7)) * 8)];
        s[n] = __builtin_amdgcn_mfma_f32_16x16x32_bf16(qf[kk], kf, s[n], 0, 0, 0);
      }
    }
    __builtin_amdgcn_s_setprio(0);
#pragma unroll
    for (int n = 0; n < 4; ++n)
#pragma unroll
      for (int j = 0; j < 4; ++j) s[n][j] *= 0.125f;
    // ---- online softmax (rows live in 16-lane groups) ----
    float ps[4][4];
#pragma unroll
    for (int j = 0; j < 4; ++j) {
      float mx = -1e30f;
#pragma unroll
      for (int n = 0; n < 4; ++n) mx = fmaxf(mx, s[n][j]);
#pragma unroll
      for (int off = 8; off; off >>= 1) mx = fmaxf(mx, __shfl_xor(mx, off));
      const float mn = fmaxf(mrun[j], mx);
      const float alpha = __expf(mrun[j] - mn);
      mrun[j] = mn;
      float rs = 0.f;
#pragma unroll
      for (int n = 0; n < 4; ++n) {
        float p = __expf(s[n][j] - mn);
        ps[n][j] = p;
        rs += p;
      }
#pragma unroll
      for (int off = 8; off; off >>= 1) rs += __shfl_xor(rs, off);
      lrun[j] = lrun[j] * alpha + rs;
#pragma unroll
      for (int c = 0; c < 4; ++c) o[c][j] *= alpha;
    }
    // ---- P -> LDS (wave-local rows, swizzled) ----
#pragma unroll
    for (int n = 0; n < 4; ++n)
#pragma unroll
      for (int j = 0; j < 4; ++j) {
        const int Rp = w * 16 + lk4 * 4 + j;
        const int e = n * 16 + lr;
        Ps[Rp * 64 + (((e >> 3) ^ (Rp & 7)) * 8) + (e & 7)] = (bf16)ps[n][j];
      }
    // ---- PV ----
    bf16x8 pa[2];
#pragma unroll
    for (int kk = 0; kk < 2; ++kk)
      pa[kk] = *(const bf16x8*)&Ps[(w * 16 + lr) * 64 + (((kk * 4 + lk4) ^ (lr & 7)) * 8)];
    __builtin_amdgcn_s_setprio(1);
#pragma unroll
    for (int c = 0; c < 4; ++c)
#pragma unroll
      for (int kk = 0; kk < 2; ++kk) {
        bf16x8 vf = *(const bf16x8*)&VTs[(c * 16 + lr) * 64 + (((kk * 4 + lk4) ^ (lr & 7)) * 8)];
        o[c] = __builtin_amdgcn_mfma_f32_16x16x32_bf16(pa[kk], vf, o[c], 0, 0, 0);
      }
    __builtin_amdgcn_s_setprio(0);
    __syncthreads();
  }
  float inv[4];
#pragma unroll
  for (int j = 0; j < 4; ++j) inv[j] = 1.f / lrun[j];
#pragma unroll
  for (int c = 0; c < 4; ++c)
#pragma unroll
    for (int j = 0; j < 4; ++j)
      out[(size_t)(b * 2048 + q0 + lk4 * 4 + j) * 1024 + h * 64 + c * 16 + lr] =
          (bf16)(o[c][j] * inv[j]);
}

// ---------------- launch ----------------
extern "C" void kernel_launch(void* const* d_in, const int* in_sizes, int n_in,
                              void* d_out, int out_size, void* d_ws, size_t ws_size,
                              hipStream_t stream) {
  const float* x      = (const float*)d_in[0];
  const float* w_qkv  = (const float*)d_in[1];
  const float* w_proj = (const float*)d_in[2];
  const float* b_proj = (const float*)d_in[3];
  const float* ln1_g  = (const float*)d_in[4];
  const float* ln1_b  = (const float*)d_in[5];
  const float* ln2_g  = (const float*)d_in[6];
  const float* ln2_b  = (const float*)d_in[7];
  const float* w_fc1  = (const float*)d_in[8];
  const float* b_fc1  = (const float*)d_in[9];
  const float* w_fc2  = (const float*)d_in[10];
  const float* b_fc2  = (const float*)d_in[11];

  char* W = (char*)d_ws;
  bf16* wqkvb = (bf16*)(W + 0);                    //  6,291,456
  bf16* wprojb = (bf16*)(W + 6291456);             //  2,097,152
  bf16* wfc1b = (bf16*)(W + 8388608);              //  8,388,608
  bf16* wfc2b = (bf16*)(W + 16777216);             //  8,388,608
  bf16* xn    = (bf16*)(W + 25165824);             //  8,388,608
  bf16* qkvb  = (bf16*)(W + 33554432);             // 25,165,824
  bf16* attnb = (bf16*)(W + 58720256);             //  8,388,608
  float* x2   = (float*)(W + 67108864);            // 16,777,216
  bf16* hbuf  = (bf16*)(W + 83886080);             // 33,554,432
  float* outf = (float*)d_out;

  // weight conversions
  f2b_kernel<<<3072, 256, 0, stream>>>(w_qkv, wqkvb, 3145728);
  f2b_kernel<<<1024, 256, 0, stream>>>(w_proj, wprojb, 1048576);
  f2b_kernel<<<4096, 256, 0, stream>>>(w_fc1, wfc1b, 4194304);
  f2b_kernel<<<4096, 256, 0, stream>>>(w_fc2, wfc2b, 4194304);

  // LN1
  ln_kernel<<<4096, 256, 0, stream>>>(x, ln1_g, ln1_b, xn);
  // QKV GEMM: [4096,3072]
  gemm_bt<0><<<dim3(24, 32), 256, 0, stream>>>(xn, wqkvb, qkvb, nullptr, nullptr, nullptr,
                                               4096, 3072, 1024);
  // attention
  flash_kernel<<<dim3(32, 32), 256, 0, stream>>>(qkvb, attnb);
  // proj + bias + residual -> x2 (fp32)
  gemm_bt<2><<<dim3(8, 32), 256, 0, stream>>>(attnb, wprojb, nullptr, x2, b_proj, x,
                                              4096, 1024, 1024);
  // LN2
  ln_kernel<<<4096, 256, 0, stream>>>(x2, ln2_g, ln2_b, xn);
  // FC1 + bias + GELU
  gemm_bt<1><<<dim3(32, 32), 256, 0, stream>>>(xn, wfc1b, hbuf, nullptr, b_fc1, nullptr,
                                               4096, 4096, 1024);
  // FC2 + bias + residual -> out (fp32)
  gemm_bt<2><<<dim3(8, 32), 256, 0, stream>>>(hbuf, wfc2b, nullptr, outf, b_fc2, x2,
                                              4096, 1024, 4096);
}

// Round 3
// 315.295 us; speedup vs baseline: 1.2860x; 1.0869x over previous
//
#include <hip/hip_runtime.h>
#include <hip/hip_bf16.h>
#include <math.h>

typedef __bf16 bf16;
typedef __attribute__((ext_vector_type(8))) __bf16 bf16x8;
typedef __attribute__((ext_vector_type(4))) __bf16 bf16x4;
typedef __attribute__((ext_vector_type(4))) float f32x4;

#define DEV static __device__ __forceinline__

typedef const void __attribute__((address_space(1)))* gptr_t;
typedef void __attribute__((address_space(3)))* lptr_t;

DEV void async16(const void* g, void* l) {
  __builtin_amdgcn_global_load_lds((gptr_t)g, (lptr_t)l, 16, 0, 0);
}

// ---------------- fp32 -> bf16 convert (weights) ----------------
__global__ __launch_bounds__(256) void f2b_kernel(const float* __restrict__ in,
                                                  bf16* __restrict__ out, int n) {
  int i = (blockIdx.x * 256 + threadIdx.x) * 4;
  if (i + 3 < n) {
    float4 v = *(const float4*)(in + i);
    out[i + 0] = (bf16)v.x;
    out[i + 1] = (bf16)v.y;
    out[i + 2] = (bf16)v.z;
    out[i + 3] = (bf16)v.w;
  }
}

// ---------------- LayerNorm: fp32 in -> bf16 out, row = 1024 ----------------
__global__ __launch_bounds__(256) void ln_kernel(const float* __restrict__ in,
                                                 const float* __restrict__ g,
                                                 const float* __restrict__ b,
                                                 bf16* __restrict__ out) {
  const int row = blockIdx.x;
  const int tid = threadIdx.x;
  float4 v = ((const float4*)(in + (size_t)row * 1024))[tid];
  float s = v.x + v.y + v.z + v.w;
  float s2 = v.x * v.x + v.y * v.y + v.z * v.z + v.w * v.w;
#pragma unroll
  for (int off = 1; off < 64; off <<= 1) {
    s += __shfl_xor(s, off);
    s2 += __shfl_xor(s2, off);
  }
  __shared__ float red[8];
  int w = tid >> 6, lane = tid & 63;
  if (lane == 0) { red[w] = s; red[4 + w] = s2; }
  __syncthreads();
  s = red[0] + red[1] + red[2] + red[3];
  s2 = red[4] + red[5] + red[6] + red[7];
  const float mean = s * (1.f / 1024.f);
  const float var = s2 * (1.f / 1024.f) - mean * mean;
  const float rstd = rsqrtf(var + 1e-5f);
  float4 gv = ((const float4*)g)[tid];
  float4 bv = ((const float4*)b)[tid];
  bf16* orow = out + (size_t)row * 1024 + tid * 4;
  orow[0] = (bf16)((v.x - mean) * rstd * gv.x + bv.x);
  orow[1] = (bf16)((v.y - mean) * rstd * gv.y + bv.y);
  orow[2] = (bf16)((v.z - mean) * rstd * gv.z + bv.z);
  orow[3] = (bf16)((v.w - mean) * rstd * gv.w + bv.w);
}

// ---------------- GEMM: C[M,N] = A[M,K] * B[N,K]^T  (+epilogue) ----------------
template <int EPI>
__global__ __launch_bounds__(256, 2) void gemm_bt(const bf16* __restrict__ A,
                                                  const bf16* __restrict__ B,
                                                  bf16* __restrict__ outb,
                                                  float* __restrict__ outf,
                                                  const float* __restrict__ bias,
                                                  const float* __restrict__ resid,
                                                  int M, int N, int K) {
  __shared__ bf16 As[128 * 64];
  __shared__ bf16 Bs[128 * 64];
  const int tid = threadIdx.x;
  const int lane = tid & 63, w = tid >> 6;
  const int lr = lane & 15, lk = (lane >> 4) * 8;
  const int wr = (w >> 1) * 64, wc = (w & 1) * 64;
  const int brow = blockIdx.y * 128, bcol = blockIdx.x * 128;
  const int sr = tid >> 3, sc = (tid & 7) * 8;
  f32x4 acc[4][4] = {};
  const bf16* Ab = A + (size_t)(brow + sr) * K + sc;
  const bf16* Bb = B + (size_t)(bcol + sr) * K + sc;
  for (int k0 = 0; k0 < K; k0 += 64) {
#pragma unroll
    for (int i = 0; i < 4; ++i) {
      async16(Ab + (size_t)(i * 32) * K + k0, &As[(i * 32 + sr) * 64 + sc]);
      async16(Bb + (size_t)(i * 32) * K + k0, &Bs[(i * 32 + sr) * 64 + sc]);
    }
    __syncthreads();
#pragma unroll
    for (int kk = 0; kk < 2; ++kk) {
      bf16x8 af[4], bfr[4];
#pragma unroll
      for (int m = 0; m < 4; ++m)
        af[m] = *(const bf16x8*)&As[(wr + m * 16 + lr) * 64 + kk * 32 + lk];
#pragma unroll
      for (int n = 0; n < 4; ++n)
        bfr[n] = *(const bf16x8*)&Bs[(wc + n * 16 + lr) * 64 + kk * 32 + lk];
#pragma unroll
      for (int m = 0; m < 4; ++m)
#pragma unroll
        for (int n = 0; n < 4; ++n)
          acc[m][n] = __builtin_amdgcn_mfma_f32_16x16x32_bf16(af[m], bfr[n], acc[m][n], 0, 0, 0);
    }
    __syncthreads();
  }
  const int r0 = brow + wr + (lane >> 4) * 4;
  const int c0 = bcol + wc + lr;
#pragma unroll
  for (int m = 0; m < 4; ++m)
#pragma unroll
    for (int n = 0; n < 4; ++n)
#pragma unroll
      for (int j = 0; j < 4; ++j) {
        const int r = r0 + m * 16 + j;
        const int c = c0 + n * 16;
        float v = acc[m][n][j];
        if (EPI == 0) {
          outb[(size_t)r * N + c] = (bf16)v;
        } else if (EPI == 1) {
          v += bias[c];
          v = 0.5f * v * (1.0f + erff(v * 0.70710678118654752f));
          outb[(size_t)r * N + c] = (bf16)v;
        } else {
          v += bias[c] + resid[(size_t)r * N + c];
          outf[(size_t)r * N + c] = v;
        }
      }
}

// ---------------- Flash attention (swapped-operand, dbuf, 1 barrier/tile) ----------------
// qkv: [4096, 3072] bf16, row = b*2048+n, col = which*1024 + h*64 + d
// out: [4096, 1024] bf16 (head-concat)
// QK^T computed as mfma(K,Q) -> S^T[kv][q]: lane owns q = lane&15 (softmax lane-local).
// PV computed as mfma(V^T,P^T) -> O^T[d][q]: alpha/lrun rescale lane-local, no broadcasts.
// All LDS tiles [row][64 bf16], 16B-chunk XOR swizzle: chunk ^= (row&7).
__global__ __launch_bounds__(256, 4) void flash_kernel(const bf16* __restrict__ qkv,
                                                       bf16* __restrict__ out) {
  const int qt = blockIdx.x;       // 0..31 (q tile of 64)
  const int bh = blockIdx.y;       // 0..31
  const int b = bh >> 4, h = bh & 15;
  const int tid = threadIdx.x;
  const int lane = tid & 63, w = tid >> 6;
  const int lr = lane & 15, lk4 = lane >> 4;
  const bf16* Qp = qkv + (size_t)(b * 2048) * 3072 + h * 64;
  const bf16* Kp = Qp + 1024;
  const bf16* Vp = Qp + 2048;
  __shared__ bf16 Ks[2][64 * 64];
  __shared__ bf16 VTs[2][64 * 64];
  __shared__ bf16 Ps[64 * 64];
  const int qw0 = qt * 64 + w * 16;
  bf16x8 qf[2];
#pragma unroll
  for (int kk = 0; kk < 2; ++kk)
    qf[kk] = *(const bf16x8*)(Qp + (size_t)(qw0 + lr) * 3072 + kk * 32 + lk4 * 8);
  f32x4 o[4] = {};
  float mrun = -1e30f, lrun = 0.f;
  const float SC = 0.125f * 1.44269504f;  // head-scale * log2(e)
  const int sr = tid >> 3, sc8 = tid & 7;
  const int vd = tid & 63, vkc = (tid >> 6) * 16, vc0 = vkc >> 3;
  const int prow = (w * 16 + lr) * 64;  // P/pb row base (q-row of this lane)
  bf16 vv[16];
  // ---- prologue: stage tile 0 ----
#pragma unroll
  for (int i = 0; i < 2; ++i) {
    const int r = i * 32 + sr;
    async16(Kp + (size_t)r * 3072 + (sc8 ^ (r & 7)) * 8, &Ks[0][r * 64 + sc8 * 8]);
  }
#pragma unroll
  for (int j = 0; j < 16; ++j) vv[j] = Vp[(size_t)(vkc + j) * 3072 + vd];
  {
    bf16x8 a, c;
#pragma unroll
    for (int j = 0; j < 8; ++j) { a[j] = vv[j]; c[j] = vv[8 + j]; }
    *(bf16x8*)&VTs[0][vd * 64 + ((vc0 ^ (vd & 7)) * 8)] = a;
    *(bf16x8*)&VTs[0][vd * 64 + (((vc0 + 1) ^ (vd & 7)) * 8)] = c;
  }
  __syncthreads();
  for (int t = 0; t < 32; ++t) {
    const int cur = t & 1, nxt = cur ^ 1;
    // ---- issue next-tile prefetch (K -> LDS async, V -> regs) ----
    if (t < 31) {
      const int kv0n = (t + 1) * 64;
#pragma unroll
      for (int i = 0; i < 2; ++i) {
        const int r = i * 32 + sr;
        async16(Kp + (size_t)(kv0n + r) * 3072 + (sc8 ^ (r & 7)) * 8,
                &Ks[nxt][r * 64 + sc8 * 8]);
      }
#pragma unroll
      for (int j = 0; j < 16; ++j) vv[j] = Vp[(size_t)(kv0n + vkc + j) * 3072 + vd];
    }
    // ---- S^T = K Q^T (lane: q = lr, kv = n*16 + lk4*4 + j) ----
    f32x4 st[4] = {};
    __builtin_amdgcn_s_setprio(1);
#pragma unroll
    for (int n = 0; n < 4; ++n)
#pragma unroll
      for (int kk = 0; kk < 2; ++kk) {
        bf16x8 kf = *(const bf16x8*)&Ks[cur][(n * 16 + lr) * 64 + (((kk * 4 + lk4) ^ (lr & 7)) * 8)];
        st[n] = __builtin_amdgcn_mfma_f32_16x16x32_bf16(kf, qf[kk], st[n], 0, 0, 0);
      }
    __builtin_amdgcn_s_setprio(0);
    // ---- online softmax, fully lane-local except 2+2 shfls ----
    float sv[4][4];
    float mx = -1e30f;
#pragma unroll
    for (int n = 0; n < 4; ++n)
#pragma unroll
      for (int j = 0; j < 4; ++j) {
        sv[n][j] = st[n][j] * SC;
        mx = fmaxf(mx, sv[n][j]);
      }
    mx = fmaxf(mx, __shfl_xor(mx, 16));
    mx = fmaxf(mx, __shfl_xor(mx, 32));
    const bool skip = __all(mx <= mrun + 8.0f);
    const float mn = skip ? mrun : fmaxf(mrun, mx);
    float rs = 0.f;
#pragma unroll
    for (int n = 0; n < 4; ++n) {
      float p0 = exp2f(sv[n][0] - mn);
      float p1 = exp2f(sv[n][1] - mn);
      float p2 = exp2f(sv[n][2] - mn);
      float p3 = exp2f(sv[n][3] - mn);
      rs += (p0 + p1) + (p2 + p3);
      bf16x4 pk;
      pk[0] = (bf16)p0; pk[1] = (bf16)p1; pk[2] = (bf16)p2; pk[3] = (bf16)p3;
      *(bf16x4*)&Ps[prow + (((n * 2 + (lk4 >> 1)) ^ (lr & 7)) * 8) + (lk4 & 1) * 4] = pk;
    }
    rs += __shfl_xor(rs, 16);
    rs += __shfl_xor(rs, 32);
    if (!skip) {
      const float alpha = exp2f(mrun - mn);
      lrun = lrun * alpha + rs;
      mrun = mn;
#pragma unroll
      for (int c = 0; c < 4; ++c)
#pragma unroll
        for (int j = 0; j < 4; ++j) o[c][j] *= alpha;
    } else {
      lrun += rs;
    }
    // ---- O^T += V^T P^T (lane: q = lr, d = c*16 + lk4*4 + j) ----
    bf16x8 pb[2];
#pragma unroll
    for (int kk = 0; kk < 2; ++kk)
      pb[kk] = *(const bf16x8*)&Ps[prow + (((kk * 4 + lk4) ^ (lr & 7)) * 8)];
    __builtin_amdgcn_s_setprio(1);
#pragma unroll
    for (int c = 0; c < 4; ++c)
#pragma unroll
      for (int kk = 0; kk < 2; ++kk) {
        bf16x8 vfr = *(const bf16x8*)&VTs[cur][(c * 16 + lr) * 64 + (((kk * 4 + lk4) ^ (lr & 7)) * 8)];
        o[c] = __builtin_amdgcn_mfma_f32_16x16x32_bf16(vfr, pb[kk], o[c], 0, 0, 0);
      }
    __builtin_amdgcn_s_setprio(0);
    // ---- late write of prefetched V^T (T14 split) ----
    if (t < 31) {
      bf16x8 a, c;
#pragma unroll
      for (int j = 0; j < 8; ++j) { a[j] = vv[j]; c[j] = vv[8 + j]; }
      *(bf16x8*)&VTs[nxt][vd * 64 + ((vc0 ^ (vd & 7)) * 8)] = a;
      *(bf16x8*)&VTs[nxt][vd * 64 + (((vc0 + 1) ^ (vd & 7)) * 8)] = c;
    }
    __syncthreads();
  }
  const float inv = 1.f / lrun;  // lane-local (q = lr)
#pragma unroll
  for (int c = 0; c < 4; ++c) {
    bf16x4 ov;
#pragma unroll
    for (int j = 0; j < 4; ++j) ov[j] = (bf16)(o[c][j] * inv);
    *(bf16x4*)&out[(size_t)(b * 2048 + qw0 + lr) * 1024 + h * 64 + c * 16 + lk4 * 4] = ov;
  }
}

// ---------------- launch ----------------
extern "C" void kernel_launch(void* const* d_in, const int* in_sizes, int n_in,
                              void* d_out, int out_size, void* d_ws, size_t ws_size,
                              hipStream_t stream) {
  const float* x      = (const float*)d_in[0];
  const float* w_qkv  = (const float*)d_in[1];
  const float* w_proj = (const float*)d_in[2];
  const float* b_proj = (const float*)d_in[3];
  const float* ln1_g  = (const float*)d_in[4];
  const float* ln1_b  = (const float*)d_in[5];
  const float* ln2_g  = (const float*)d_in[6];
  const float* ln2_b  = (const float*)d_in[7];
  const float* w_fc1  = (const float*)d_in[8];
  const float* b_fc1  = (const float*)d_in[9];
  const float* w_fc2  = (const float*)d_in[10];
  const float* b_fc2  = (const float*)d_in[11];

  char* W = (char*)d_ws;
  bf16* wqkvb = (bf16*)(W + 0);                    //  6,291,456
  bf16* wprojb = (bf16*)(W + 6291456);             //  2,097,152
  bf16* wfc1b = (bf16*)(W + 8388608);              //  8,388,608
  bf16* wfc2b = (bf16*)(W + 16777216);             //  8,388,608
  bf16* xn    = (bf16*)(W + 25165824);             //  8,388,608
  bf16* qkvb  = (bf16*)(W + 33554432);             // 25,165,824
  bf16* attnb = (bf16*)(W + 58720256);             //  8,388,608
  float* x2   = (float*)(W + 67108864);            // 16,777,216
  bf16* hbuf  = (bf16*)(W + 83886080);             // 33,554,432
  float* outf = (float*)d_out;

  // weight conversions
  f2b_kernel<<<3072, 256, 0, stream>>>(w_qkv, wqkvb, 3145728);
  f2b_kernel<<<1024, 256, 0, stream>>>(w_proj, wprojb, 1048576);
  f2b_kernel<<<4096, 256, 0, stream>>>(w_fc1, wfc1b, 4194304);
  f2b_kernel<<<4096, 256, 0, stream>>>(w_fc2, wfc2b, 4194304);

  // LN1
  ln_kernel<<<4096, 256, 0, stream>>>(x, ln1_g, ln1_b, xn);
  // QKV GEMM: [4096,3072]
  gemm_bt<0><<<dim3(24, 32), 256, 0, stream>>>(xn, wqkvb, qkvb, nullptr, nullptr, nullptr,
                                               4096, 3072, 1024);
  // attention
  flash_kernel<<<dim3(32, 32), 256, 0, stream>>>(qkvb, attnb);
  // proj + bias + residual -> x2 (fp32)
  gemm_bt<2><<<dim3(8, 32), 256, 0, stream>>>(attnb, wprojb, nullptr, x2, b_proj, x,
                                              4096, 1024, 1024);
  // LN2
  ln_kernel<<<4096, 256, 0, stream>>>(x2, ln2_g, ln2_b, xn);
  // FC1 + bias + GELU
  gemm_bt<1><<<dim3(32, 32), 256, 0, stream>>>(xn, wfc1b, hbuf, nullptr, b_fc1, nullptr,
                                               4096, 4096, 1024);
  // FC2 + bias + residual -> out (fp32)
  gemm_bt<2><<<dim3(8, 32), 256, 0, stream>>>(hbuf, wfc2b, nullptr, outf, b_fc2, x2,
                                              4096, 1024, 4096);
}

// Round 4
// 297.236 us; speedup vs baseline: 1.3642x; 1.0608x over previous
//
#include <hip/hip_runtime.h>
#include <hip/hip_bf16.h>
#include <math.h>

typedef __bf16 bf16;
typedef __attribute__((ext_vector_type(8))) __bf16 bf16x8;
typedef __attribute__((ext_vector_type(4))) __bf16 bf16x4;
typedef __attribute__((ext_vector_type(4))) float f32x4;

#define DEV static __device__ __forceinline__

typedef const void __attribute__((address_space(1)))* gptr_t;
typedef void __attribute__((address_space(3)))* lptr_t;

DEV void async16(const void* g, void* l) {
  __builtin_amdgcn_global_load_lds((gptr_t)g, (lptr_t)l, 16, 0, 0);
}

DEV void wg_barrier() {
  __builtin_amdgcn_sched_barrier(0);
  __builtin_amdgcn_s_barrier();
  __builtin_amdgcn_sched_barrier(0);
}

// ---------------- fused fp32 -> bf16 convert (4 weight arrays) ----------------
__global__ __launch_bounds__(256) void f2b4_kernel(const float* __restrict__ s0,
                                                   const float* __restrict__ s1,
                                                   const float* __restrict__ s2,
                                                   const float* __restrict__ s3,
                                                   bf16* __restrict__ d0, bf16* __restrict__ d1,
                                                   bf16* __restrict__ d2, bf16* __restrict__ d3,
                                                   int n0, int n1, int n2, int n3) {
  int i = (blockIdx.x * 256 + threadIdx.x) * 4;
  const float* s;
  bf16* d;
  int off;
  if (i < n0) { s = s0; d = d0; off = i; }
  else if (i < n0 + n1) { s = s1; d = d1; off = i - n0; }
  else if (i < n0 + n1 + n2) { s = s2; d = d2; off = i - n0 - n1; }
  else if (i < n0 + n1 + n2 + n3) { s = s3; d = d3; off = i - n0 - n1 - n2; }
  else return;
  float4 v = *(const float4*)(s + off);
  d[off + 0] = (bf16)v.x;
  d[off + 1] = (bf16)v.y;
  d[off + 2] = (bf16)v.z;
  d[off + 3] = (bf16)v.w;
}

// ---------------- LayerNorm: fp32 in -> bf16 out, row = 1024 ----------------
__global__ __launch_bounds__(256) void ln_kernel(const float* __restrict__ in,
                                                 const float* __restrict__ g,
                                                 const float* __restrict__ b,
                                                 bf16* __restrict__ out) {
  const int row = blockIdx.x;
  const int tid = threadIdx.x;
  float4 v = ((const float4*)(in + (size_t)row * 1024))[tid];
  float s = v.x + v.y + v.z + v.w;
  float s2 = v.x * v.x + v.y * v.y + v.z * v.z + v.w * v.w;
#pragma unroll
  for (int off = 1; off < 64; off <<= 1) {
    s += __shfl_xor(s, off);
    s2 += __shfl_xor(s2, off);
  }
  __shared__ float red[8];
  int w = tid >> 6, lane = tid & 63;
  if (lane == 0) { red[w] = s; red[4 + w] = s2; }
  __syncthreads();
  s = red[0] + red[1] + red[2] + red[3];
  s2 = red[4] + red[5] + red[6] + red[7];
  const float mean = s * (1.f / 1024.f);
  const float var = s2 * (1.f / 1024.f) - mean * mean;
  const float rstd = rsqrtf(var + 1e-5f);
  float4 gv = ((const float4*)g)[tid];
  float4 bv = ((const float4*)b)[tid];
  bf16* orow = out + (size_t)row * 1024 + tid * 4;
  orow[0] = (bf16)((v.x - mean) * rstd * gv.x + bv.x);
  orow[1] = (bf16)((v.y - mean) * rstd * gv.y + bv.y);
  orow[2] = (bf16)((v.z - mean) * rstd * gv.z + bv.z);
  orow[3] = (bf16)((v.w - mean) * rstd * gv.w + bv.w);
}

// ---------------- 256x256 deep-pipelined GEMM: C = A * B^T ----------------
// 512 threads = 8 waves (2M x 4N), per-wave 128x64, BK=64, 2 LDS buffers,
// 2-tiles-ahead prefetch with counted vmcnt(8) (never drains in main loop).
// LDS content XOR-swizzled at 16B-chunk granularity: chunk ^= (row&7),
// applied by pre-swizzling the global source column (LDS dest stays linear).
// EPI 0: bf16 out. EPI 1: bias + exact GELU -> bf16.
template <int EPI>
__global__ __launch_bounds__(512, 2) void gemm256(const bf16* __restrict__ A,
                                                  const bf16* __restrict__ B,
                                                  bf16* __restrict__ outb,
                                                  const float* __restrict__ bias,
                                                  int M, int N, int K, int gridN) {
  __shared__ bf16 As[2][256 * 64];
  __shared__ bf16 Bs[2][256 * 64];
  const int nwg = gridDim.x;
  const int bid = blockIdx.x;
  const int swz = (bid & 7) * (nwg >> 3) + (bid >> 3);  // nwg % 8 == 0 (bijective)
  const int bx = swz % gridN, by = swz / gridN;
  const int brow = by * 256, bcol = bx * 256;
  const int tid = threadIdx.x;
  const int lane = tid & 63, wid = tid >> 6;
  const int wm = wid >> 2, wn = wid & 3;
  const int lr = lane & 15, lk4 = lane >> 4;
  const int strow = tid >> 3, stc = tid & 7;  // staging: row-in-sweep, stored chunk
  const int NT = K >> 6;
  f32x4 acc[8][4] = {};

#define STAGE(tt, bb)                                                                   \
  {                                                                                     \
    const int k0_ = (tt)*64;                                                            \
    _Pragma("unroll") for (int s_ = 0; s_ < 4; ++s_) {                                  \
      const int r_ = s_ * 64 + strow;                                                   \
      const int g_ = (stc ^ (strow & 7)) * 8;                                           \
      async16(A + (size_t)(brow + r_) * K + k0_ + g_, &As[bb][r_ * 64 + stc * 8]);      \
      async16(B + (size_t)(bcol + r_) * K + k0_ + g_, &Bs[bb][r_ * 64 + stc * 8]);      \
    }                                                                                   \
  }

  STAGE(0, 0);
  STAGE(1, 1);
  asm volatile("s_waitcnt vmcnt(8)" ::: "memory");
  wg_barrier();

  for (int t = 0; t < NT; ++t) {
    const int cur = t & 1;
    // ---- 1. LDS -> register fragments (all reads of buf[cur]) ----
    bf16x8 af[8][2], bfr[4][2];
#pragma unroll
    for (int m = 0; m < 8; ++m)
#pragma unroll
      for (int kk = 0; kk < 2; ++kk) {
        const int row = wm * 128 + m * 16 + lr;
        const int kc = kk * 4 + lk4;
        af[m][kk] = *(const bf16x8*)&As[cur][row * 64 + ((kc ^ (row & 7)) * 8)];
      }
#pragma unroll
    for (int n = 0; n < 4; ++n)
#pragma unroll
      for (int kk = 0; kk < 2; ++kk) {
        const int row = wn * 64 + n * 16 + lr;
        const int kc = kk * 4 + lk4;
        bfr[n][kk] = *(const bf16x8*)&Bs[cur][row * 64 + ((kc ^ (row & 7)) * 8)];
      }
    asm volatile("s_waitcnt lgkmcnt(0)" ::: "memory");
    wg_barrier();  // all waves done reading buf[cur] -> writable
    // ---- 2. prefetch tile t+2 into the buffer just freed ----
    if (t + 2 < NT) STAGE(t + 2, cur);
    // ---- 3. register-only MFMA (64) ----
    __builtin_amdgcn_s_setprio(1);
#pragma unroll
    for (int m = 0; m < 8; ++m)
#pragma unroll
      for (int n = 0; n < 4; ++n) {
        acc[m][n] = __builtin_amdgcn_mfma_f32_16x16x32_bf16(af[m][0], bfr[n][0], acc[m][n], 0, 0, 0);
        acc[m][n] = __builtin_amdgcn_mfma_f32_16x16x32_bf16(af[m][1], bfr[n][1], acc[m][n], 0, 0, 0);
      }
    __builtin_amdgcn_s_setprio(0);
    // ---- 4. tile t+1 ready: counted wait (t+2's 8 calls stay in flight) ----
    if (t + 1 < NT) {
      if (t + 2 < NT) {
        asm volatile("s_waitcnt vmcnt(8)" ::: "memory");
      } else {
        asm volatile("s_waitcnt vmcnt(0)" ::: "memory");
      }
      wg_barrier();
    }
  }
#undef STAGE
  // ---- epilogue ----
  const int r0 = brow + wm * 128 + lk4 * 4;
  const int c0 = bcol + wn * 64 + lr;
  float bias_v[4];
  if (EPI == 1) {
#pragma unroll
    for (int n = 0; n < 4; ++n) bias_v[n] = bias[c0 + n * 16];
  }
#pragma unroll
  for (int m = 0; m < 8; ++m)
#pragma unroll
    for (int n = 0; n < 4; ++n)
#pragma unroll
      for (int j = 0; j < 4; ++j) {
        const int r = r0 + m * 16 + j;
        const int c = c0 + n * 16;
        float v = acc[m][n][j];
        if (EPI == 1) {
          v += bias_v[n];
          v = 0.5f * v * (1.0f + erff(v * 0.70710678118654752f));
        }
        outb[(size_t)r * N + c] = (bf16)v;
      }
}

// ---------------- 128x128 GEMM (m97 structure): C = A * B^T, fp32 epilogues ----------------
// EPI 2: bias + resid -> fp32 (used for proj and FC2 where N=1024 needs a 256-block grid).
template <int EPI>
__global__ __launch_bounds__(256, 2) void gemm_bt(const bf16* __restrict__ A,
                                                  const bf16* __restrict__ B,
                                                  bf16* __restrict__ outb,
                                                  float* __restrict__ outf,
                                                  const float* __restrict__ bias,
                                                  const float* __restrict__ resid,
                                                  int M, int N, int K) {
  __shared__ bf16 As[128 * 64];
  __shared__ bf16 Bs[128 * 64];
  const int tid = threadIdx.x;
  const int lane = tid & 63, w = tid >> 6;
  const int lr = lane & 15, lk = (lane >> 4) * 8;
  const int wr = (w >> 1) * 64, wc = (w & 1) * 64;
  const int brow = blockIdx.y * 128, bcol = blockIdx.x * 128;
  const int sr = tid >> 3, sc = (tid & 7) * 8;
  f32x4 acc[4][4] = {};
  const bf16* Ab = A + (size_t)(brow + sr) * K + sc;
  const bf16* Bb = B + (size_t)(bcol + sr) * K + sc;
  for (int k0 = 0; k0 < K; k0 += 64) {
#pragma unroll
    for (int i = 0; i < 4; ++i) {
      async16(Ab + (size_t)(i * 32) * K + k0, &As[(i * 32 + sr) * 64 + sc]);
      async16(Bb + (size_t)(i * 32) * K + k0, &Bs[(i * 32 + sr) * 64 + sc]);
    }
    __syncthreads();
#pragma unroll
    for (int kk = 0; kk < 2; ++kk) {
      bf16x8 af[4], bfr[4];
#pragma unroll
      for (int m = 0; m < 4; ++m)
        af[m] = *(const bf16x8*)&As[(wr + m * 16 + lr) * 64 + kk * 32 + lk];
#pragma unroll
      for (int n = 0; n < 4; ++n)
        bfr[n] = *(const bf16x8*)&Bs[(wc + n * 16 + lr) * 64 + kk * 32 + lk];
#pragma unroll
      for (int m = 0; m < 4; ++m)
#pragma unroll
        for (int n = 0; n < 4; ++n)
          acc[m][n] = __builtin_amdgcn_mfma_f32_16x16x32_bf16(af[m], bfr[n], acc[m][n], 0, 0, 0);
    }
    __syncthreads();
  }
  const int r0 = brow + wr + (lane >> 4) * 4;
  const int c0 = bcol + wc + lr;
#pragma unroll
  for (int m = 0; m < 4; ++m)
#pragma unroll
    for (int n = 0; n < 4; ++n)
#pragma unroll
      for (int j = 0; j < 4; ++j) {
        const int r = r0 + m * 16 + j;
        const int c = c0 + n * 16;
        float v = acc[m][n][j];
        if (EPI == 0) {
          outb[(size_t)r * N + c] = (bf16)v;
        } else if (EPI == 1) {
          v += bias[c];
          v = 0.5f * v * (1.0f + erff(v * 0.70710678118654752f));
          outb[(size_t)r * N + c] = (bf16)v;
        } else {
          v += bias[c] + resid[(size_t)r * N + c];
          outf[(size_t)r * N + c] = v;
        }
      }
}

// ---------------- Flash attention (swapped-operand, dbuf, 1 barrier/tile) ----------------
__global__ __launch_bounds__(256, 4) void flash_kernel(const bf16* __restrict__ qkv,
                                                       bf16* __restrict__ out) {
  const int qt = blockIdx.x;
  const int bh = blockIdx.y;
  const int b = bh >> 4, h = bh & 15;
  const int tid = threadIdx.x;
  const int lane = tid & 63, w = tid >> 6;
  const int lr = lane & 15, lk4 = lane >> 4;
  const bf16* Qp = qkv + (size_t)(b * 2048) * 3072 + h * 64;
  const bf16* Kp = Qp + 1024;
  const bf16* Vp = Qp + 2048;
  __shared__ bf16 Ks[2][64 * 64];
  __shared__ bf16 VTs[2][64 * 64];
  __shared__ bf16 Ps[64 * 64];
  const int qw0 = qt * 64 + w * 16;
  bf16x8 qf[2];
#pragma unroll
  for (int kk = 0; kk < 2; ++kk)
    qf[kk] = *(const bf16x8*)(Qp + (size_t)(qw0 + lr) * 3072 + kk * 32 + lk4 * 8);
  f32x4 o[4] = {};
  float mrun = -1e30f, lrun = 0.f;
  const float SC = 0.125f * 1.44269504f;
  const int sr = tid >> 3, sc8 = tid & 7;
  const int vd = tid & 63, vkc = (tid >> 6) * 16, vc0 = vkc >> 3;
  const int prow = (w * 16 + lr) * 64;
  bf16 vv[16];
#pragma unroll
  for (int i = 0; i < 2; ++i) {
    const int r = i * 32 + sr;
    async16(Kp + (size_t)r * 3072 + (sc8 ^ (r & 7)) * 8, &Ks[0][r * 64 + sc8 * 8]);
  }
#pragma unroll
  for (int j = 0; j < 16; ++j) vv[j] = Vp[(size_t)(vkc + j) * 3072 + vd];
  {
    bf16x8 a, c;
#pragma unroll
    for (int j = 0; j < 8; ++j) { a[j] = vv[j]; c[j] = vv[8 + j]; }
    *(bf16x8*)&VTs[0][vd * 64 + ((vc0 ^ (vd & 7)) * 8)] = a;
    *(bf16x8*)&VTs[0][vd * 64 + (((vc0 + 1) ^ (vd & 7)) * 8)] = c;
  }
  __syncthreads();
  for (int t = 0; t < 32; ++t) {
    const int cur = t & 1, nxt = cur ^ 1;
    if (t < 31) {
      const int kv0n = (t + 1) * 64;
#pragma unroll
      for (int i = 0; i < 2; ++i) {
        const int r = i * 32 + sr;
        async16(Kp + (size_t)(kv0n + r) * 3072 + (sc8 ^ (r & 7)) * 8,
                &Ks[nxt][r * 64 + sc8 * 8]);
      }
#pragma unroll
      for (int j = 0; j < 16; ++j) vv[j] = Vp[(size_t)(kv0n + vkc + j) * 3072 + vd];
    }
    f32x4 st[4] = {};
    __builtin_amdgcn_s_setprio(1);
#pragma unroll
    for (int n = 0; n < 4; ++n)
#pragma unroll
      for (int kk = 0; kk < 2; ++kk) {
        bf16x8 kf = *(const bf16x8*)&Ks[cur][(n * 16 + lr) * 64 + (((kk * 4 + lk4) ^ (lr & 7)) * 8)];
        st[n] = __builtin_amdgcn_mfma_f32_16x16x32_bf16(kf, qf[kk], st[n], 0, 0, 0);
      }
    __builtin_amdgcn_s_setprio(0);
    float sv[4][4];
    float mx = -1e30f;
#pragma unroll
    for (int n = 0; n < 4; ++n)
#pragma unroll
      for (int j = 0; j < 4; ++j) {
        sv[n][j] = st[n][j] * SC;
        mx = fmaxf(mx, sv[n][j]);
      }
    mx = fmaxf(mx, __shfl_xor(mx, 16));
    mx = fmaxf(mx, __shfl_xor(mx, 32));
    const bool skip = __all(mx <= mrun + 8.0f);
    const float mn = skip ? mrun : fmaxf(mrun, mx);
    float rs = 0.f;
#pragma unroll
    for (int n = 0; n < 4; ++n) {
      float p0 = exp2f(sv[n][0] - mn);
      float p1 = exp2f(sv[n][1] - mn);
      float p2 = exp2f(sv[n][2] - mn);
      float p3 = exp2f(sv[n][3] - mn);
      rs += (p0 + p1) + (p2 + p3);
      bf16x4 pk;
      pk[0] = (bf16)p0; pk[1] = (bf16)p1; pk[2] = (bf16)p2; pk[3] = (bf16)p3;
      *(bf16x4*)&Ps[prow + (((n * 2 + (lk4 >> 1)) ^ (lr & 7)) * 8) + (lk4 & 1) * 4] = pk;
    }
    rs += __shfl_xor(rs, 16);
    rs += __shfl_xor(rs, 32);
    if (!skip) {
      const float alpha = exp2f(mrun - mn);
      lrun = lrun * alpha + rs;
      mrun = mn;
#pragma unroll
      for (int c = 0; c < 4; ++c)
#pragma unroll
        for (int j = 0; j < 4; ++j) o[c][j] *= alpha;
    } else {
      lrun += rs;
    }
    bf16x8 pb[2];
#pragma unroll
    for (int kk = 0; kk < 2; ++kk)
      pb[kk] = *(const bf16x8*)&Ps[prow + (((kk * 4 + lk4) ^ (lr & 7)) * 8)];
    __builtin_amdgcn_s_setprio(1);
#pragma unroll
    for (int c = 0; c < 4; ++c)
#pragma unroll
      for (int kk = 0; kk < 2; ++kk) {
        bf16x8 vfr = *(const bf16x8*)&VTs[cur][(c * 16 + lr) * 64 + (((kk * 4 + lk4) ^ (lr & 7)) * 8)];
        o[c] = __builtin_amdgcn_mfma_f32_16x16x32_bf16(vfr, pb[kk], o[c], 0, 0, 0);
      }
    __builtin_amdgcn_s_setprio(0);
    if (t < 31) {
      bf16x8 a, c;
#pragma unroll
      for (int j = 0; j < 8; ++j) { a[j] = vv[j]; c[j] = vv[8 + j]; }
      *(bf16x8*)&VTs[nxt][vd * 64 + ((vc0 ^ (vd & 7)) * 8)] = a;
      *(bf16x8*)&VTs[nxt][vd * 64 + (((vc0 + 1) ^ (vd & 7)) * 8)] = c;
    }
    __syncthreads();
  }
  const float inv = 1.f / lrun;
#pragma unroll
  for (int c = 0; c < 4; ++c) {
    bf16x4 ov;
#pragma unroll
    for (int j = 0; j < 4; ++j) ov[j] = (bf16)(o[c][j] * inv);
    *(bf16x4*)&out[(size_t)(b * 2048 + qw0 + lr) * 1024 + h * 64 + c * 16 + lk4 * 4] = ov;
  }
}

// ---------------- launch ----------------
extern "C" void kernel_launch(void* const* d_in, const int* in_sizes, int n_in,
                              void* d_out, int out_size, void* d_ws, size_t ws_size,
                              hipStream_t stream) {
  const float* x      = (const float*)d_in[0];
  const float* w_qkv  = (const float*)d_in[1];
  const float* w_proj = (const float*)d_in[2];
  const float* b_proj = (const float*)d_in[3];
  const float* ln1_g  = (const float*)d_in[4];
  const float* ln1_b  = (const float*)d_in[5];
  const float* ln2_g  = (const float*)d_in[6];
  const float* ln2_b  = (const float*)d_in[7];
  const float* w_fc1  = (const float*)d_in[8];
  const float* b_fc1  = (const float*)d_in[9];
  const float* w_fc2  = (const float*)d_in[10];
  const float* b_fc2  = (const float*)d_in[11];

  char* W = (char*)d_ws;
  bf16* wqkvb = (bf16*)(W + 0);                    //  6,291,456
  bf16* wprojb = (bf16*)(W + 6291456);             //  2,097,152
  bf16* wfc1b = (bf16*)(W + 8388608);              //  8,388,608
  bf16* wfc2b = (bf16*)(W + 16777216);             //  8,388,608
  bf16* xn    = (bf16*)(W + 25165824);             //  8,388,608
  bf16* qkvb  = (bf16*)(W + 33554432);             // 25,165,824
  bf16* attnb = (bf16*)(W + 58720256);             //  8,388,608
  float* x2   = (float*)(W + 67108864);            // 16,777,216
  bf16* hbuf  = (bf16*)(W + 83886080);             // 33,554,432
  float* outf = (float*)d_out;

  // fused weight conversions (12,582,912 elems / 4 per thread / 256 = 12288 blocks)
  f2b4_kernel<<<12288, 256, 0, stream>>>(w_qkv, w_proj, w_fc1, w_fc2,
                                         wqkvb, wprojb, wfc1b, wfc2b,
                                         3145728, 1048576, 4194304, 4194304);

  // LN1
  ln_kernel<<<4096, 256, 0, stream>>>(x, ln1_g, ln1_b, xn);
  // QKV GEMM: [4096,3072] = xn * w_qkv^T  (256² deep-pipeline, grid 12x16=192)
  gemm256<0><<<192, 512, 0, stream>>>(xn, wqkvb, qkvb, nullptr, 4096, 3072, 1024, 12);
  // attention
  flash_kernel<<<dim3(32, 32), 256, 0, stream>>>(qkvb, attnb);
  // proj + bias + residual -> x2 (fp32)
  gemm_bt<2><<<dim3(8, 32), 256, 0, stream>>>(attnb, wprojb, nullptr, x2, b_proj, x,
                                              4096, 1024, 1024);
  // LN2
  ln_kernel<<<4096, 256, 0, stream>>>(x2, ln2_g, ln2_b, xn);
  // FC1 + bias + GELU (256² deep-pipeline, grid 16x16=256)
  gemm256<1><<<256, 512, 0, stream>>>(xn, wfc1b, hbuf, b_fc1, 4096, 4096, 1024, 16);
  // FC2 + bias + residual -> out (fp32)
  gemm_bt<2><<<dim3(8, 32), 256, 0, stream>>>(hbuf, wfc2b, nullptr, outf, b_fc2, x2,
                                              4096, 1024, 4096);
}

// Round 7
// 255.243 us; speedup vs baseline: 1.5886x; 1.1645x over previous
//
#include <hip/hip_runtime.h>
#include <hip/hip_bf16.h>
#include <math.h>

typedef __bf16 bf16;
typedef __attribute__((ext_vector_type(8))) __bf16 bf16x8;
typedef __attribute__((ext_vector_type(4))) __bf16 bf16x4;
typedef __attribute__((ext_vector_type(4))) float f32x4;

#define DEV static __device__ __forceinline__

typedef const void __attribute__((address_space(1)))* gptr_t;
typedef void __attribute__((address_space(3)))* lptr_t;

DEV void async16(const void* g, void* l) {
  __builtin_amdgcn_global_load_lds((gptr_t)g, (lptr_t)l, 16, 0, 0);
}

DEV void wg_barrier() {
  __builtin_amdgcn_sched_barrier(0);
  __builtin_amdgcn_s_barrier();
  __builtin_amdgcn_sched_barrier(0);
}

// ---------------- fused fp32 -> bf16 convert (4 weight arrays) ----------------
__global__ __launch_bounds__(256) void f2b4_kernel(const float* __restrict__ s0,
                                                   const float* __restrict__ s1,
                                                   const float* __restrict__ s2,
                                                   const float* __restrict__ s3,
                                                   bf16* __restrict__ d0, bf16* __restrict__ d1,
                                                   bf16* __restrict__ d2, bf16* __restrict__ d3,
                                                   int n0, int n1, int n2, int n3) {
  int i = (blockIdx.x * 256 + threadIdx.x) * 4;
  const float* s;
  bf16* d;
  int off;
  if (i < n0) { s = s0; d = d0; off = i; }
  else if (i < n0 + n1) { s = s1; d = d1; off = i - n0; }
  else if (i < n0 + n1 + n2) { s = s2; d = d2; off = i - n0 - n1; }
  else if (i < n0 + n1 + n2 + n3) { s = s3; d = d3; off = i - n0 - n1 - n2; }
  else return;
  float4 v = *(const float4*)(s + off);
  d[off + 0] = (bf16)v.x;
  d[off + 1] = (bf16)v.y;
  d[off + 2] = (bf16)v.z;
  d[off + 3] = (bf16)v.w;
}

// ---------------- LayerNorm: fp32 in -> bf16 out, row = 1024 ----------------
__global__ __launch_bounds__(256) void ln_kernel(const float* __restrict__ in,
                                                 const float* __restrict__ g,
                                                 const float* __restrict__ b,
                                                 bf16* __restrict__ out) {
  const int row = blockIdx.x;
  const int tid = threadIdx.x;
  float4 v = ((const float4*)(in + (size_t)row * 1024))[tid];
  float s = v.x + v.y + v.z + v.w;
  float s2 = v.x * v.x + v.y * v.y + v.z * v.z + v.w * v.w;
#pragma unroll
  for (int off = 1; off < 64; off <<= 1) {
    s += __shfl_xor(s, off);
    s2 += __shfl_xor(s2, off);
  }
  __shared__ float red[8];
  int w = tid >> 6, lane = tid & 63;
  if (lane == 0) { red[w] = s; red[4 + w] = s2; }
  __syncthreads();
  s = red[0] + red[1] + red[2] + red[3];
  s2 = red[4] + red[5] + red[6] + red[7];
  const float mean = s * (1.f / 1024.f);
  const float var = s2 * (1.f / 1024.f) - mean * mean;
  const float rstd = rsqrtf(var + 1e-5f);
  float4 gv = ((const float4*)g)[tid];
  float4 bv = ((const float4*)b)[tid];
  bf16* orow = out + (size_t)row * 1024 + tid * 4;
  orow[0] = (bf16)((v.x - mean) * rstd * gv.x + bv.x);
  orow[1] = (bf16)((v.y - mean) * rstd * gv.y + bv.y);
  orow[2] = (bf16)((v.z - mean) * rstd * gv.z + bv.z);
  orow[3] = (bf16)((v.w - mean) * rstd * gv.w + bv.w);
}

// ---------------- 256x256 deep-pipelined GEMM: C = A * B^T ----------------
// EPI 0: bf16 out. EPI 1: bias + exact GELU -> bf16.
template <int EPI>
__global__ __launch_bounds__(512, 2) void gemm256(const bf16* __restrict__ A,
                                                  const bf16* __restrict__ B,
                                                  bf16* __restrict__ outb,
                                                  const float* __restrict__ bias,
                                                  int M, int N, int K, int gridN) {
  __shared__ bf16 As[2][256 * 64];
  __shared__ bf16 Bs[2][256 * 64];
  const int nwg = gridDim.x;
  const int bid = blockIdx.x;
  const int swz = (bid & 7) * (nwg >> 3) + (bid >> 3);  // nwg % 8 == 0 (bijective)
  const int bx = swz % gridN, by = swz / gridN;
  const int brow = by * 256, bcol = bx * 256;
  const int tid = threadIdx.x;
  const int lane = tid & 63, wid = tid >> 6;
  const int wm = wid >> 2, wn = wid & 3;
  const int lr = lane & 15, lk4 = lane >> 4;
  const int strow = tid >> 3, stc = tid & 7;
  const int NT = K >> 6;
  f32x4 acc[8][4] = {};

#define STAGE(tt, bb)                                                                   \
  {                                                                                     \
    const int k0_ = (tt)*64;                                                            \
    _Pragma("unroll") for (int s_ = 0; s_ < 4; ++s_) {                                  \
      const int r_ = s_ * 64 + strow;                                                   \
      const int g_ = (stc ^ (strow & 7)) * 8;                                           \
      async16(A + (size_t)(brow + r_) * K + k0_ + g_, &As[bb][r_ * 64 + stc * 8]);      \
      async16(B + (size_t)(bcol + r_) * K + k0_ + g_, &Bs[bb][r_ * 64 + stc * 8]);      \
    }                                                                                   \
  }

  STAGE(0, 0);
  STAGE(1, 1);
  asm volatile("s_waitcnt vmcnt(8)" ::: "memory");
  wg_barrier();

  for (int t = 0; t < NT; ++t) {
    const int cur = t & 1;
    bf16x8 af[8][2], bfr[4][2];
#pragma unroll
    for (int m = 0; m < 8; ++m)
#pragma unroll
      for (int kk = 0; kk < 2; ++kk) {
        const int row = wm * 128 + m * 16 + lr;
        const int kc = kk * 4 + lk4;
        af[m][kk] = *(const bf16x8*)&As[cur][row * 64 + ((kc ^ (row & 7)) * 8)];
      }
#pragma unroll
    for (int n = 0; n < 4; ++n)
#pragma unroll
      for (int kk = 0; kk < 2; ++kk) {
        const int row = wn * 64 + n * 16 + lr;
        const int kc = kk * 4 + lk4;
        bfr[n][kk] = *(const bf16x8*)&Bs[cur][row * 64 + ((kc ^ (row & 7)) * 8)];
      }
    asm volatile("s_waitcnt lgkmcnt(0)" ::: "memory");
    wg_barrier();
    if (t + 2 < NT) STAGE(t + 2, cur);
    __builtin_amdgcn_s_setprio(1);
#pragma unroll
    for (int m = 0; m < 8; ++m)
#pragma unroll
      for (int n = 0; n < 4; ++n) {
        acc[m][n] = __builtin_amdgcn_mfma_f32_16x16x32_bf16(af[m][0], bfr[n][0], acc[m][n], 0, 0, 0);
        acc[m][n] = __builtin_amdgcn_mfma_f32_16x16x32_bf16(af[m][1], bfr[n][1], acc[m][n], 0, 0, 0);
      }
    __builtin_amdgcn_s_setprio(0);
    if (t + 1 < NT) {
      if (t + 2 < NT) {
        asm volatile("s_waitcnt vmcnt(8)" ::: "memory");
      } else {
        asm volatile("s_waitcnt vmcnt(0)" ::: "memory");
      }
      wg_barrier();
    }
  }
#undef STAGE
  const int r0 = brow + wm * 128 + lk4 * 4;
  const int c0 = bcol + wn * 64 + lr;
  float bias_v[4];
  if (EPI == 1) {
#pragma unroll
    for (int n = 0; n < 4; ++n) bias_v[n] = bias[c0 + n * 16];
  }
#pragma unroll
  for (int m = 0; m < 8; ++m)
#pragma unroll
    for (int n = 0; n < 4; ++n)
#pragma unroll
      for (int j = 0; j < 4; ++j) {
        const int r = r0 + m * 16 + j;
        const int c = c0 + n * 16;
        float v = acc[m][n][j];
        if (EPI == 1) {
          v += bias_v[n];
          v = 0.5f * v * (1.0f + erff(v * 0.70710678118654752f));
        }
        outb[(size_t)r * N + c] = (bf16)v;
      }
}

// ---------------- 128x128 deep-pipelined GEMM: outf = A*B^T + bias + resid ----------------
__global__ __launch_bounds__(512, 2) void gemm128(const bf16* __restrict__ A,
                                                  const bf16* __restrict__ B,
                                                  float* __restrict__ outf,
                                                  const float* __restrict__ bias,
                                                  const float* __restrict__ resid,
                                                  int M, int N, int K, int gridN) {
  __shared__ bf16 As[2][128 * 64];
  __shared__ bf16 Bs[2][128 * 64];
  const int nwg = gridDim.x;
  const int bid = blockIdx.x;
  const int swz = (bid & 7) * (nwg >> 3) + (bid >> 3);  // nwg % 8 == 0
  const int bx = swz % gridN, by = swz / gridN;
  const int brow = by * 128, bcol = bx * 128;
  const int tid = threadIdx.x;
  const int lane = tid & 63, wid = tid >> 6;
  const int wm = wid >> 2, wn = wid & 3;  // 2 x 4 waves; per-wave 64x32
  const int lr = lane & 15, lk4 = lane >> 4;
  const int strow = tid >> 3, stc = tid & 7;
  const int NT = K >> 6;
  f32x4 acc[4][2] = {};

#define STAGE1(tt, bb)                                                                  \
  {                                                                                     \
    const int k0_ = (tt)*64;                                                            \
    _Pragma("unroll") for (int s_ = 0; s_ < 2; ++s_) {                                  \
      const int r_ = s_ * 64 + strow;                                                   \
      const int g_ = (stc ^ (strow & 7)) * 8;                                           \
      async16(A + (size_t)(brow + r_) * K + k0_ + g_, &As[bb][r_ * 64 + stc * 8]);      \
      async16(B + (size_t)(bcol + r_) * K + k0_ + g_, &Bs[bb][r_ * 64 + stc * 8]);      \
    }                                                                                   \
  }

  STAGE1(0, 0);
  STAGE1(1, 1);
  asm volatile("s_waitcnt vmcnt(4)" ::: "memory");
  wg_barrier();

  for (int t = 0; t < NT; ++t) {
    const int cur = t & 1;
    bf16x8 af[4][2], bfr[2][2];
#pragma unroll
    for (int m = 0; m < 4; ++m)
#pragma unroll
      for (int kk = 0; kk < 2; ++kk) {
        const int row = wm * 64 + m * 16 + lr;
        const int kc = kk * 4 + lk4;
        af[m][kk] = *(const bf16x8*)&As[cur][row * 64 + ((kc ^ (row & 7)) * 8)];
      }
#pragma unroll
    for (int n = 0; n < 2; ++n)
#pragma unroll
      for (int kk = 0; kk < 2; ++kk) {
        const int row = wn * 32 + n * 16 + lr;
        const int kc = kk * 4 + lk4;
        bfr[n][kk] = *(const bf16x8*)&Bs[cur][row * 64 + ((kc ^ (row & 7)) * 8)];
      }
    asm volatile("s_waitcnt lgkmcnt(0)" ::: "memory");
    wg_barrier();
    if (t + 2 < NT) STAGE1(t + 2, cur);
    __builtin_amdgcn_s_setprio(1);
#pragma unroll
    for (int m = 0; m < 4; ++m)
#pragma unroll
      for (int n = 0; n < 2; ++n) {
        acc[m][n] = __builtin_amdgcn_mfma_f32_16x16x32_bf16(af[m][0], bfr[n][0], acc[m][n], 0, 0, 0);
        acc[m][n] = __builtin_amdgcn_mfma_f32_16x16x32_bf16(af[m][1], bfr[n][1], acc[m][n], 0, 0, 0);
      }
    __builtin_amdgcn_s_setprio(0);
    if (t + 1 < NT) {
      if (t + 2 < NT) {
        asm volatile("s_waitcnt vmcnt(4)" ::: "memory");
      } else {
        asm volatile("s_waitcnt vmcnt(0)" ::: "memory");
      }
      wg_barrier();
    }
  }
#undef STAGE1
  const int r0 = brow + wm * 64 + lk4 * 4;
  const int c0 = bcol + wn * 32 + lr;
#pragma unroll
  for (int m = 0; m < 4; ++m)
#pragma unroll
    for (int n = 0; n < 2; ++n)
#pragma unroll
      for (int j = 0; j < 4; ++j) {
        const int r = r0 + m * 16 + j;
        const int c = c0 + n * 16;
        outf[(size_t)r * N + c] = acc[m][n][j] + bias[c] + resid[(size_t)r * N + c];
      }
}

// ---------------- Flash attention (swapped-operand, dbuf, register V-transpose) ----------------
// QK^T as mfma(K,Q) -> S^T; PV as mfma(V^T,P^T) -> O^T. LDS tiles [row][64],
// 16B-chunk XOR swizzle chunk ^= (row&7). V^T staged via registers (proven R2/R3 path).
__global__ __launch_bounds__(256, 4) void flash_kernel(const bf16* __restrict__ qkv,
                                                       bf16* __restrict__ out) {
  const int qt = blockIdx.x;
  const int bh = blockIdx.y;
  const int b = bh >> 4, h = bh & 15;
  const int tid = threadIdx.x;
  const int lane = tid & 63, w = tid >> 6;
  const int lr = lane & 15, lk4 = lane >> 4;
  const bf16* Qp = qkv + (size_t)(b * 2048) * 3072 + h * 64;
  const bf16* Kp = Qp + 1024;
  const bf16* Vp = Qp + 2048;
  __shared__ bf16 Ks[2][64 * 64];
  __shared__ bf16 VTs[2][64 * 64];
  __shared__ bf16 Ps[64 * 64];
  const int qw0 = qt * 64 + w * 16;
  const float SC = 0.125f * 1.44269504f;   // head-scale * log2(e), applied in fp32
  const float THRU = 8.0f / SC;            // defer-max threshold in raw-score units
  bf16x8 qf[2];
#pragma unroll
  for (int kk = 0; kk < 2; ++kk)
    qf[kk] = *(const bf16x8*)(Qp + (size_t)(qw0 + lr) * 3072 + kk * 32 + lk4 * 8);
  f32x4 o[4] = {};
  float mrun = -1e30f, lrun = 0.f;
  const int sr = tid >> 3, sc8 = tid & 7;
  const int vd = tid & 63, vkc = (tid >> 6) * 16, vc0 = vkc >> 3;
  const int prow = (w * 16 + lr) * 64;
  bf16 vv[16];
  // ---- prologue: stage tile 0 ----
#pragma unroll
  for (int i = 0; i < 2; ++i) {
    const int r = i * 32 + sr;
    async16(Kp + (size_t)r * 3072 + (sc8 ^ (r & 7)) * 8, &Ks[0][r * 64 + sc8 * 8]);
  }
#pragma unroll
  for (int j = 0; j < 16; ++j) vv[j] = Vp[(size_t)(vkc + j) * 3072 + vd];
  {
    bf16x8 a, c;
#pragma unroll
    for (int j = 0; j < 8; ++j) { a[j] = vv[j]; c[j] = vv[8 + j]; }
    *(bf16x8*)&VTs[0][vd * 64 + ((vc0 ^ (vd & 7)) * 8)] = a;
    *(bf16x8*)&VTs[0][vd * 64 + (((vc0 + 1) ^ (vd & 7)) * 8)] = c;
  }
  __syncthreads();
  for (int t = 0; t < 32; ++t) {
    const int cur = t & 1, nxt = cur ^ 1;
    // ---- prefetch next tile (K -> LDS async, V -> regs) ----
    if (t < 31) {
      const size_t kv0n = (size_t)(t + 1) * 64;
#pragma unroll
      for (int i = 0; i < 2; ++i) {
        const int r = i * 32 + sr;
        async16(Kp + (kv0n + r) * 3072 + (sc8 ^ (r & 7)) * 8, &Ks[nxt][r * 64 + sc8 * 8]);
      }
#pragma unroll
      for (int j = 0; j < 16; ++j) vv[j] = Vp[(kv0n + vkc + j) * 3072 + vd];
    }
    // ---- S^T = K Q^T (lane: q = lr, kv = n*16 + lk4*4 + j) ----
    f32x4 st[4] = {};
    __builtin_amdgcn_s_setprio(1);
#pragma unroll
    for (int n = 0; n < 4; ++n)
#pragma unroll
      for (int kk = 0; kk < 2; ++kk) {
        bf16x8 kf = *(const bf16x8*)&Ks[cur][(n * 16 + lr) * 64 + (((kk * 4 + lk4) ^ (lr & 7)) * 8)];
        st[n] = __builtin_amdgcn_mfma_f32_16x16x32_bf16(kf, qf[kk], st[n], 0, 0, 0);
      }
    __builtin_amdgcn_s_setprio(0);
    // ---- online softmax (lane-local; 2+2 shfls). m tracked in RAW units. ----
    float mx = -1e30f;
#pragma unroll
    for (int n = 0; n < 4; ++n)
#pragma unroll
      for (int j = 0; j < 4; ++j) mx = fmaxf(mx, st[n][j]);
    mx = fmaxf(mx, __shfl_xor(mx, 16));
    mx = fmaxf(mx, __shfl_xor(mx, 32));
    const bool skip = __all(mx <= mrun + THRU);
    const float mn = skip ? mrun : fmaxf(mrun, mx);
    const float mnS = mn * SC;
    float rs = 0.f;
#pragma unroll
    for (int n = 0; n < 4; ++n) {
      float p0 = exp2f(fmaf(st[n][0], SC, -mnS));
      float p1 = exp2f(fmaf(st[n][1], SC, -mnS));
      float p2 = exp2f(fmaf(st[n][2], SC, -mnS));
      float p3 = exp2f(fmaf(st[n][3], SC, -mnS));
      rs += (p0 + p1) + (p2 + p3);
      bf16x4 pk;
      pk[0] = (bf16)p0; pk[1] = (bf16)p1; pk[2] = (bf16)p2; pk[3] = (bf16)p3;
      *(bf16x4*)&Ps[prow + (((n * 2 + (lk4 >> 1)) ^ (lr & 7)) * 8) + (lk4 & 1) * 4] = pk;
    }
    rs += __shfl_xor(rs, 16);
    rs += __shfl_xor(rs, 32);
    if (!skip) {
      const float alpha = exp2f(fmaf(mrun, SC, -mnS));
      lrun = lrun * alpha + rs;
      mrun = mn;
#pragma unroll
      for (int c = 0; c < 4; ++c)
#pragma unroll
        for (int j = 0; j < 4; ++j) o[c][j] *= alpha;
    } else {
      lrun += rs;
    }
    // ---- P^T operand (own wave's rows only) ----
    bf16x8 pb[2];
#pragma unroll
    for (int kk = 0; kk < 2; ++kk)
      pb[kk] = *(const bf16x8*)&Ps[prow + (((kk * 4 + lk4) ^ (lr & 7)) * 8)];
    // ---- O^T += V^T P^T ----
    __builtin_amdgcn_s_setprio(1);
#pragma unroll
    for (int c = 0; c < 4; ++c)
#pragma unroll
      for (int kk = 0; kk < 2; ++kk) {
        bf16x8 vfr = *(const bf16x8*)&VTs[cur][(c * 16 + lr) * 64 + (((kk * 4 + lk4) ^ (lr & 7)) * 8)];
        o[c] = __builtin_amdgcn_mfma_f32_16x16x32_bf16(vfr, pb[kk], o[c], 0, 0, 0);
      }
    __builtin_amdgcn_s_setprio(0);
    // ---- late write of prefetched V^T ----
    if (t < 31) {
      bf16x8 a, c;
#pragma unroll
      for (int j = 0; j < 8; ++j) { a[j] = vv[j]; c[j] = vv[8 + j]; }
      *(bf16x8*)&VTs[nxt][vd * 64 + ((vc0 ^ (vd & 7)) * 8)] = a;
      *(bf16x8*)&VTs[nxt][vd * 64 + (((vc0 + 1) ^ (vd & 7)) * 8)] = c;
    }
    __syncthreads();
  }
  const float inv = 1.f / lrun;
#pragma unroll
  for (int c = 0; c < 4; ++c) {
    bf16x4 ov;
#pragma unroll
    for (int j = 0; j < 4; ++j) ov[j] = (bf16)(o[c][j] * inv);
    *(bf16x4*)&out[(size_t)(b * 2048 + qw0 + lr) * 1024 + h * 64 + c * 16 + lk4 * 4] = ov;
  }
}

// ---------------- launch ----------------
extern "C" void kernel_launch(void* const* d_in, const int* in_sizes, int n_in,
                              void* d_out, int out_size, void* d_ws, size_t ws_size,
                              hipStream_t stream) {
  const float* x      = (const float*)d_in[0];
  const float* w_qkv  = (const float*)d_in[1];
  const float* w_proj = (const float*)d_in[2];
  const float* b_proj = (const float*)d_in[3];
  const float* ln1_g  = (const float*)d_in[4];
  const float* ln1_b  = (const float*)d_in[5];
  const float* ln2_g  = (const float*)d_in[6];
  const float* ln2_b  = (const float*)d_in[7];
  const float* w_fc1  = (const float*)d_in[8];
  const float* b_fc1  = (const float*)d_in[9];
  const float* w_fc2  = (const float*)d_in[10];
  const float* b_fc2  = (const float*)d_in[11];

  char* W = (char*)d_ws;
  bf16* wqkvb = (bf16*)(W + 0);                    //  6,291,456
  bf16* wprojb = (bf16*)(W + 6291456);             //  2,097,152
  bf16* wfc1b = (bf16*)(W + 8388608);              //  8,388,608
  bf16* wfc2b = (bf16*)(W + 16777216);             //  8,388,608
  bf16* xn    = (bf16*)(W + 25165824);             //  8,388,608
  bf16* qkvb  = (bf16*)(W + 33554432);             // 25,165,824
  bf16* attnb = (bf16*)(W + 58720256);             //  8,388,608
  float* x2   = (float*)(W + 67108864);            // 16,777,216
  bf16* hbuf  = (bf16*)(W + 83886080);             // 33,554,432
  float* outf = (float*)d_out;

  f2b4_kernel<<<12288, 256, 0, stream>>>(w_qkv, w_proj, w_fc1, w_fc2,
                                         wqkvb, wprojb, wfc1b, wfc2b,
                                         3145728, 1048576, 4194304, 4194304);

  // LN1
  ln_kernel<<<4096, 256, 0, stream>>>(x, ln1_g, ln1_b, xn);
  // QKV GEMM (256² deep-pipeline, grid 12x16=192)
  gemm256<0><<<192, 512, 0, stream>>>(xn, wqkvb, qkvb, nullptr, 4096, 3072, 1024, 12);
  // attention
  flash_kernel<<<dim3(32, 32), 256, 0, stream>>>(qkvb, attnb);
  // proj + bias + residual -> x2 (128² deep-pipeline, grid 32x8=256)
  gemm128<<<256, 512, 0, stream>>>(attnb, wprojb, x2, b_proj, x, 4096, 1024, 1024, 8);
  // LN2
  ln_kernel<<<4096, 256, 0, stream>>>(x2, ln2_g, ln2_b, xn);
  // FC1 + bias + GELU (256² deep-pipeline, grid 16x16=256)
  gemm256<1><<<256, 512, 0, stream>>>(xn, wfc1b, hbuf, b_fc1, 4096, 4096, 1024, 16);
  // FC2 + bias + residual -> out (128² deep-pipeline, grid 32x8=256)
  gemm128<<<256, 512, 0, stream>>>(hbuf, wfc2b, outf, b_fc2, x2, 4096, 1024, 4096, 8);
}

// Round 8
// 253.179 us; speedup vs baseline: 1.6016x; 1.0082x over previous
//
#include <hip/hip_runtime.h>
#include <hip/hip_bf16.h>
#include <math.h>

typedef __bf16 bf16;
typedef __attribute__((ext_vector_type(8))) __bf16 bf16x8;
typedef __attribute__((ext_vector_type(4))) __bf16 bf16x4;
typedef __attribute__((ext_vector_type(4))) float f32x4;

#define DEV static __device__ __forceinline__

typedef const void __attribute__((address_space(1)))* gptr_t;
typedef void __attribute__((address_space(3)))* lptr_t;

DEV void async16(const void* g, void* l) {
  __builtin_amdgcn_global_load_lds((gptr_t)g, (lptr_t)l, 16, 0, 0);
}

DEV void wg_barrier() {
  __builtin_amdgcn_sched_barrier(0);
  __builtin_amdgcn_s_barrier();
  __builtin_amdgcn_sched_barrier(0);
}

// ---------------- fused fp32 -> bf16 convert (4 weight arrays) ----------------
__global__ __launch_bounds__(256) void f2b4_kernel(const float* __restrict__ s0,
                                                   const float* __restrict__ s1,
                                                   const float* __restrict__ s2,
                                                   const float* __restrict__ s3,
                                                   bf16* __restrict__ d0, bf16* __restrict__ d1,
                                                   bf16* __restrict__ d2, bf16* __restrict__ d3,
                                                   int n0, int n1, int n2, int n3) {
  int i = (blockIdx.x * 256 + threadIdx.x) * 4;
  const float* s;
  bf16* d;
  int off;
  if (i < n0) { s = s0; d = d0; off = i; }
  else if (i < n0 + n1) { s = s1; d = d1; off = i - n0; }
  else if (i < n0 + n1 + n2) { s = s2; d = d2; off = i - n0 - n1; }
  else if (i < n0 + n1 + n2 + n3) { s = s3; d = d3; off = i - n0 - n1 - n2; }
  else return;
  float4 v = *(const float4*)(s + off);
  d[off + 0] = (bf16)v.x;
  d[off + 1] = (bf16)v.y;
  d[off + 2] = (bf16)v.z;
  d[off + 3] = (bf16)v.w;
}

// ---------------- LayerNorm: fp32 in -> bf16 out, row = 1024 ----------------
__global__ __launch_bounds__(256) void ln_kernel(const float* __restrict__ in,
                                                 const float* __restrict__ g,
                                                 const float* __restrict__ b,
                                                 bf16* __restrict__ out) {
  const int row = blockIdx.x;
  const int tid = threadIdx.x;
  float4 v = ((const float4*)(in + (size_t)row * 1024))[tid];
  float s = v.x + v.y + v.z + v.w;
  float s2 = v.x * v.x + v.y * v.y + v.z * v.z + v.w * v.w;
#pragma unroll
  for (int off = 1; off < 64; off <<= 1) {
    s += __shfl_xor(s, off);
    s2 += __shfl_xor(s2, off);
  }
  __shared__ float red[8];
  int w = tid >> 6, lane = tid & 63;
  if (lane == 0) { red[w] = s; red[4 + w] = s2; }
  __syncthreads();
  s = red[0] + red[1] + red[2] + red[3];
  s2 = red[4] + red[5] + red[6] + red[7];
  const float mean = s * (1.f / 1024.f);
  const float var = s2 * (1.f / 1024.f) - mean * mean;
  const float rstd = rsqrtf(var + 1e-5f);
  float4 gv = ((const float4*)g)[tid];
  float4 bv = ((const float4*)b)[tid];
  bf16* orow = out + (size_t)row * 1024 + tid * 4;
  orow[0] = (bf16)((v.x - mean) * rstd * gv.x + bv.x);
  orow[1] = (bf16)((v.y - mean) * rstd * gv.y + bv.y);
  orow[2] = (bf16)((v.z - mean) * rstd * gv.z + bv.z);
  orow[3] = (bf16)((v.w - mean) * rstd * gv.w + bv.w);
}

// ---------------- 256x256 deep-pipelined GEMM: C = A * B^T ----------------
// EPI 0: bf16 out. EPI 1: bias + exact GELU -> bf16.
template <int EPI>
__global__ __launch_bounds__(512, 2) void gemm256(const bf16* __restrict__ A,
                                                  const bf16* __restrict__ B,
                                                  bf16* __restrict__ outb,
                                                  const float* __restrict__ bias,
                                                  int M, int N, int K, int gridN) {
  __shared__ bf16 As[2][256 * 64];
  __shared__ bf16 Bs[2][256 * 64];
  const int nwg = gridDim.x;
  const int bid = blockIdx.x;
  const int swz = (bid & 7) * (nwg >> 3) + (bid >> 3);  // nwg % 8 == 0 (bijective)
  const int bx = swz % gridN, by = swz / gridN;
  const int brow = by * 256, bcol = bx * 256;
  const int tid = threadIdx.x;
  const int lane = tid & 63, wid = tid >> 6;
  const int wm = wid >> 2, wn = wid & 3;
  const int lr = lane & 15, lk4 = lane >> 4;
  const int strow = tid >> 3, stc = tid & 7;
  const int NT = K >> 6;
  f32x4 acc[8][4] = {};

#define STAGE(tt, bb)                                                                   \
  {                                                                                     \
    const int k0_ = (tt)*64;                                                            \
    _Pragma("unroll") for (int s_ = 0; s_ < 4; ++s_) {                                  \
      const int r_ = s_ * 64 + strow;                                                   \
      const int g_ = (stc ^ (strow & 7)) * 8;                                           \
      async16(A + (size_t)(brow + r_) * K + k0_ + g_, &As[bb][r_ * 64 + stc * 8]);      \
      async16(B + (size_t)(bcol + r_) * K + k0_ + g_, &Bs[bb][r_ * 64 + stc * 8]);      \
    }                                                                                   \
  }

  STAGE(0, 0);
  STAGE(1, 1);
  asm volatile("s_waitcnt vmcnt(8)" ::: "memory");
  wg_barrier();

  for (int t = 0; t < NT; ++t) {
    const int cur = t & 1;
    bf16x8 af[8][2], bfr[4][2];
#pragma unroll
    for (int m = 0; m < 8; ++m)
#pragma unroll
      for (int kk = 0; kk < 2; ++kk) {
        const int row = wm * 128 + m * 16 + lr;
        const int kc = kk * 4 + lk4;
        af[m][kk] = *(const bf16x8*)&As[cur][row * 64 + ((kc ^ (row & 7)) * 8)];
      }
#pragma unroll
    for (int n = 0; n < 4; ++n)
#pragma unroll
      for (int kk = 0; kk < 2; ++kk) {
        const int row = wn * 64 + n * 16 + lr;
        const int kc = kk * 4 + lk4;
        bfr[n][kk] = *(const bf16x8*)&Bs[cur][row * 64 + ((kc ^ (row & 7)) * 8)];
      }
    asm volatile("s_waitcnt lgkmcnt(0)" ::: "memory");
    wg_barrier();
    if (t + 2 < NT) STAGE(t + 2, cur);
    __builtin_amdgcn_s_setprio(1);
#pragma unroll
    for (int m = 0; m < 8; ++m)
#pragma unroll
      for (int n = 0; n < 4; ++n) {
        acc[m][n] = __builtin_amdgcn_mfma_f32_16x16x32_bf16(af[m][0], bfr[n][0], acc[m][n], 0, 0, 0);
        acc[m][n] = __builtin_amdgcn_mfma_f32_16x16x32_bf16(af[m][1], bfr[n][1], acc[m][n], 0, 0, 0);
      }
    __builtin_amdgcn_s_setprio(0);
    if (t + 1 < NT) {
      if (t + 2 < NT) {
        asm volatile("s_waitcnt vmcnt(8)" ::: "memory");
      } else {
        asm volatile("s_waitcnt vmcnt(0)" ::: "memory");
      }
      wg_barrier();
    }
  }
#undef STAGE
  const int r0 = brow + wm * 128 + lk4 * 4;
  const int c0 = bcol + wn * 64 + lr;
  float bias_v[4];
  if (EPI == 1) {
#pragma unroll
    for (int n = 0; n < 4; ++n) bias_v[n] = bias[c0 + n * 16];
  }
#pragma unroll
  for (int m = 0; m < 8; ++m)
#pragma unroll
    for (int n = 0; n < 4; ++n)
#pragma unroll
      for (int j = 0; j < 4; ++j) {
        const int r = r0 + m * 16 + j;
        const int c = c0 + n * 16;
        float v = acc[m][n][j];
        if (EPI == 1) {
          v += bias_v[n];
          v = 0.5f * v * (1.0f + erff(v * 0.70710678118654752f));
        }
        outb[(size_t)r * N + c] = (bf16)v;
      }
}

// ---------------- 128x128 deep-pipelined GEMM: outf = A*B^T + bias + resid ----------------
__global__ __launch_bounds__(512, 2) void gemm128(const bf16* __restrict__ A,
                                                  const bf16* __restrict__ B,
                                                  float* __restrict__ outf,
                                                  const float* __restrict__ bias,
                                                  const float* __restrict__ resid,
                                                  int M, int N, int K, int gridN) {
  __shared__ bf16 As[2][128 * 64];
  __shared__ bf16 Bs[2][128 * 64];
  const int nwg = gridDim.x;
  const int bid = blockIdx.x;
  const int swz = (bid & 7) * (nwg >> 3) + (bid >> 3);  // nwg % 8 == 0
  const int bx = swz % gridN, by = swz / gridN;
  const int brow = by * 128, bcol = bx * 128;
  const int tid = threadIdx.x;
  const int lane = tid & 63, wid = tid >> 6;
  const int wm = wid >> 2, wn = wid & 3;  // 2 x 4 waves; per-wave 64x32
  const int lr = lane & 15, lk4 = lane >> 4;
  const int strow = tid >> 3, stc = tid & 7;
  const int NT = K >> 6;
  f32x4 acc[4][2] = {};

#define STAGE1(tt, bb)                                                                  \
  {                                                                                     \
    const int k0_ = (tt)*64;                                                            \
    _Pragma("unroll") for (int s_ = 0; s_ < 2; ++s_) {                                  \
      const int r_ = s_ * 64 + strow;                                                   \
      const int g_ = (stc ^ (strow & 7)) * 8;                                           \
      async16(A + (size_t)(brow + r_) * K + k0_ + g_, &As[bb][r_ * 64 + stc * 8]);      \
      async16(B + (size_t)(bcol + r_) * K + k0_ + g_, &Bs[bb][r_ * 64 + stc * 8]);      \
    }                                                                                   \
  }

  STAGE1(0, 0);
  STAGE1(1, 1);
  asm volatile("s_waitcnt vmcnt(4)" ::: "memory");
  wg_barrier();

  for (int t = 0; t < NT; ++t) {
    const int cur = t & 1;
    bf16x8 af[4][2], bfr[2][2];
#pragma unroll
    for (int m = 0; m < 4; ++m)
#pragma unroll
      for (int kk = 0; kk < 2; ++kk) {
        const int row = wm * 64 + m * 16 + lr;
        const int kc = kk * 4 + lk4;
        af[m][kk] = *(const bf16x8*)&As[cur][row * 64 + ((kc ^ (row & 7)) * 8)];
      }
#pragma unroll
    for (int n = 0; n < 2; ++n)
#pragma unroll
      for (int kk = 0; kk < 2; ++kk) {
        const int row = wn * 32 + n * 16 + lr;
        const int kc = kk * 4 + lk4;
        bfr[n][kk] = *(const bf16x8*)&Bs[cur][row * 64 + ((kc ^ (row & 7)) * 8)];
      }
    asm volatile("s_waitcnt lgkmcnt(0)" ::: "memory");
    wg_barrier();
    if (t + 2 < NT) STAGE1(t + 2, cur);
    __builtin_amdgcn_s_setprio(1);
#pragma unroll
    for (int m = 0; m < 4; ++m)
#pragma unroll
      for (int n = 0; n < 2; ++n) {
        acc[m][n] = __builtin_amdgcn_mfma_f32_16x16x32_bf16(af[m][0], bfr[n][0], acc[m][n], 0, 0, 0);
        acc[m][n] = __builtin_amdgcn_mfma_f32_16x16x32_bf16(af[m][1], bfr[n][1], acc[m][n], 0, 0, 0);
      }
    __builtin_amdgcn_s_setprio(0);
    if (t + 1 < NT) {
      if (t + 2 < NT) {
        asm volatile("s_waitcnt vmcnt(4)" ::: "memory");
      } else {
        asm volatile("s_waitcnt vmcnt(0)" ::: "memory");
      }
      wg_barrier();
    }
  }
#undef STAGE1
  const int r0 = brow + wm * 64 + lk4 * 4;
  const int c0 = bcol + wn * 32 + lr;
#pragma unroll
  for (int m = 0; m < 4; ++m)
#pragma unroll
    for (int n = 0; n < 2; ++n)
#pragma unroll
      for (int j = 0; j < 4; ++j) {
        const int r = r0 + m * 16 + j;
        const int c = c0 + n * 16;
        outf[(size_t)r * N + c] = acc[m][n][j] + bias[c] + resid[(size_t)r * N + c];
      }
}

// ---------------- Flash attention (QBLK=128, 8 waves, swapped-operand) ----------------
// 512 threads stage each 64x64 K/V tile cooperatively: 1 async16 (K) + 8 scalar
// V loads + 1 ds_write_b128 per thread. Per wave: 16 q-rows, softmax lane-local.
__global__ __launch_bounds__(512, 4) void flash_kernel(const bf16* __restrict__ qkv,
                                                       bf16* __restrict__ out) {
  const int qt = blockIdx.x;       // 0..15 (q tile of 128)
  const int bh = blockIdx.y;       // 0..31
  const int b = bh >> 4, h = bh & 15;
  const int tid = threadIdx.x;
  const int lane = tid & 63, w = tid >> 6;
  const int lr = lane & 15, lk4 = lane >> 4;
  const bf16* Qp = qkv + (size_t)(b * 2048) * 3072 + h * 64;
  const bf16* Kp = Qp + 1024;
  const bf16* Vp = Qp + 2048;
  __shared__ bf16 Ks[2][64 * 64];
  __shared__ bf16 VTs[2][64 * 64];
  __shared__ bf16 Ps[128 * 64];
  const int qw0 = qt * 128 + w * 16;
  const float SC = 0.125f * 1.44269504f;   // head-scale * log2(e), applied in fp32
  const float THRU = 8.0f / SC;            // defer-max threshold in raw-score units
  bf16x8 qf[2];
#pragma unroll
  for (int kk = 0; kk < 2; ++kk)
    qf[kk] = *(const bf16x8*)(Qp + (size_t)(qw0 + lr) * 3072 + kk * 32 + lk4 * 8);
  f32x4 o[4] = {};
  float mrun = -1e30f, lrun = 0.f;
  const int sr = tid >> 3, sc8 = tid & 7;          // K staging: row, chunk (512 thr = full tile)
  const int vd = tid & 63, vkc = (tid >> 6) * 8;   // V: d row, 8-kv group
  const int vch = tid >> 6;                        // chunk index 0..7
  const int prow = (w * 16 + lr) * 64;
  bf16 vv[8];
  // ---- prologue: stage tile 0 ----
  async16(Kp + (size_t)sr * 3072 + (sc8 ^ (sr & 7)) * 8, &Ks[0][sr * 64 + sc8 * 8]);
#pragma unroll
  for (int j = 0; j < 8; ++j) vv[j] = Vp[(size_t)(vkc + j) * 3072 + vd];
  {
    bf16x8 a;
#pragma unroll
    for (int j = 0; j < 8; ++j) a[j] = vv[j];
    *(bf16x8*)&VTs[0][vd * 64 + ((vch ^ (vd & 7)) * 8)] = a;
  }
  __syncthreads();
  for (int t = 0; t < 32; ++t) {
    const int cur = t & 1, nxt = cur ^ 1;
    // ---- prefetch next tile (K -> LDS async, V -> regs) ----
    if (t < 31) {
      const size_t kv0n = (size_t)(t + 1) * 64;
      async16(Kp + (kv0n + sr) * 3072 + (sc8 ^ (sr & 7)) * 8, &Ks[nxt][sr * 64 + sc8 * 8]);
#pragma unroll
      for (int j = 0; j < 8; ++j) vv[j] = Vp[(kv0n + vkc + j) * 3072 + vd];
    }
    // ---- S^T = K Q^T (lane: q = lr, kv = n*16 + lk4*4 + j) ----
    f32x4 st[4] = {};
    __builtin_amdgcn_s_setprio(1);
#pragma unroll
    for (int n = 0; n < 4; ++n)
#pragma unroll
      for (int kk = 0; kk < 2; ++kk) {
        bf16x8 kf = *(const bf16x8*)&Ks[cur][(n * 16 + lr) * 64 + (((kk * 4 + lk4) ^ (lr & 7)) * 8)];
        st[n] = __builtin_amdgcn_mfma_f32_16x16x32_bf16(kf, qf[kk], st[n], 0, 0, 0);
      }
    __builtin_amdgcn_s_setprio(0);
    // ---- online softmax (lane-local; 2+2 shfls). m tracked in RAW units. ----
    float m01 = fmaxf(fmaxf(st[0][0], st[0][1]), fmaxf(st[0][2], st[0][3]));
    float m23 = fmaxf(fmaxf(st[1][0], st[1][1]), fmaxf(st[1][2], st[1][3]));
    float m45 = fmaxf(fmaxf(st[2][0], st[2][1]), fmaxf(st[2][2], st[2][3]));
    float m67 = fmaxf(fmaxf(st[3][0], st[3][1]), fmaxf(st[3][2], st[3][3]));
    float mx = fmaxf(fmaxf(m01, m23), fmaxf(m45, m67));
    mx = fmaxf(mx, __shfl_xor(mx, 16));
    mx = fmaxf(mx, __shfl_xor(mx, 32));
    const bool skip = __all(mx <= mrun + THRU);
    const float mn = skip ? mrun : fmaxf(mrun, mx);
    const float mnS = mn * SC;
    float rs = 0.f;
#pragma unroll
    for (int n = 0; n < 4; ++n) {
      float p0 = exp2f(fmaf(st[n][0], SC, -mnS));
      float p1 = exp2f(fmaf(st[n][1], SC, -mnS));
      float p2 = exp2f(fmaf(st[n][2], SC, -mnS));
      float p3 = exp2f(fmaf(st[n][3], SC, -mnS));
      rs += (p0 + p1) + (p2 + p3);
      bf16x4 pk;
      pk[0] = (bf16)p0; pk[1] = (bf16)p1; pk[2] = (bf16)p2; pk[3] = (bf16)p3;
      *(bf16x4*)&Ps[prow + (((n * 2 + (lk4 >> 1)) ^ (lr & 7)) * 8) + (lk4 & 1) * 4] = pk;
    }
    rs += __shfl_xor(rs, 16);
    rs += __shfl_xor(rs, 32);
    if (!skip) {
      const float alpha = exp2f(fmaf(mrun, SC, -mnS));
      lrun = lrun * alpha + rs;
      mrun = mn;
#pragma unroll
      for (int c = 0; c < 4; ++c)
#pragma unroll
        for (int j = 0; j < 4; ++j) o[c][j] *= alpha;
    } else {
      lrun += rs;
    }
    // ---- P^T operand (own wave's rows only) ----
    bf16x8 pb[2];
#pragma unroll
    for (int kk = 0; kk < 2; ++kk)
      pb[kk] = *(const bf16x8*)&Ps[prow + (((kk * 4 + lk4) ^ (lr & 7)) * 8)];
    // ---- O^T += V^T P^T ----
    __builtin_amdgcn_s_setprio(1);
#pragma unroll
    for (int c = 0; c < 4; ++c)
#pragma unroll
      for (int kk = 0; kk < 2; ++kk) {
        bf16x8 vfr = *(const bf16x8*)&VTs[cur][(c * 16 + lr) * 64 + (((kk * 4 + lk4) ^ (lr & 7)) * 8)];
        o[c] = __builtin_amdgcn_mfma_f32_16x16x32_bf16(vfr, pb[kk], o[c], 0, 0, 0);
      }
    __builtin_amdgcn_s_setprio(0);
    // ---- late write of prefetched V^T ----
    if (t < 31) {
      bf16x8 a;
#pragma unroll
      for (int j = 0; j < 8; ++j) a[j] = vv[j];
      *(bf16x8*)&VTs[nxt][vd * 64 + ((vch ^ (vd & 7)) * 8)] = a;
    }
    __syncthreads();
  }
  const float inv = 1.f / lrun;
#pragma unroll
  for (int c = 0; c < 4; ++c) {
    bf16x4 ov;
#pragma unroll
    for (int j = 0; j < 4; ++j) ov[j] = (bf16)(o[c][j] * inv);
    *(bf16x4*)&out[(size_t)(b * 2048 + qw0 + lr) * 1024 + h * 64 + c * 16 + lk4 * 4] = ov;
  }
}

// ---------------- launch ----------------
extern "C" void kernel_launch(void* const* d_in, const int* in_sizes, int n_in,
                              void* d_out, int out_size, void* d_ws, size_t ws_size,
                              hipStream_t stream) {
  const float* x      = (const float*)d_in[0];
  const float* w_qkv  = (const float*)d_in[1];
  const float* w_proj = (const float*)d_in[2];
  const float* b_proj = (const float*)d_in[3];
  const float* ln1_g  = (const float*)d_in[4];
  const float* ln1_b  = (const float*)d_in[5];
  const float* ln2_g  = (const float*)d_in[6];
  const float* ln2_b  = (const float*)d_in[7];
  const float* w_fc1  = (const float*)d_in[8];
  const float* b_fc1  = (const float*)d_in[9];
  const float* w_fc2  = (const float*)d_in[10];
  const float* b_fc2  = (const float*)d_in[11];

  char* W = (char*)d_ws;
  bf16* wqkvb = (bf16*)(W + 0);                    //  6,291,456
  bf16* wprojb = (bf16*)(W + 6291456);             //  2,097,152
  bf16* wfc1b = (bf16*)(W + 8388608);              //  8,388,608
  bf16* wfc2b = (bf16*)(W + 16777216);             //  8,388,608
  bf16* xn    = (bf16*)(W + 25165824);             //  8,388,608
  bf16* qkvb  = (bf16*)(W + 33554432);             // 25,165,824
  bf16* attnb = (bf16*)(W + 58720256);             //  8,388,608
  float* x2   = (float*)(W + 67108864);            // 16,777,216
  bf16* hbuf  = (bf16*)(W + 83886080);             // 33,554,432
  float* outf = (float*)d_out;

  f2b4_kernel<<<12288, 256, 0, stream>>>(w_qkv, w_proj, w_fc1, w_fc2,
                                         wqkvb, wprojb, wfc1b, wfc2b,
                                         3145728, 1048576, 4194304, 4194304);

  // LN1
  ln_kernel<<<4096, 256, 0, stream>>>(x, ln1_g, ln1_b, xn);
  // QKV GEMM (256² deep-pipeline, grid 12x16=192)
  gemm256<0><<<192, 512, 0, stream>>>(xn, wqkvb, qkvb, nullptr, 4096, 3072, 1024, 12);
  // attention (QBLK=128, 8 waves)
  flash_kernel<<<dim3(16, 32), 512, 0, stream>>>(qkvb, attnb);
  // proj + bias + residual -> x2 (128² deep-pipeline, grid 32x8=256)
  gemm128<<<256, 512, 0, stream>>>(attnb, wprojb, x2, b_proj, x, 4096, 1024, 1024, 8);
  // LN2
  ln_kernel<<<4096, 256, 0, stream>>>(x2, ln2_g, ln2_b, xn);
  // FC1 + bias + GELU (256² deep-pipeline, grid 16x16=256)
  gemm256<1><<<256, 512, 0, stream>>>(xn, wfc1b, hbuf, b_fc1, 4096, 4096, 1024, 16);
  // FC2 + bias + residual -> out (128² deep-pipeline, grid 32x8=256)
  gemm128<<<256, 512, 0, stream>>>(hbuf, wfc2b, outf, b_fc2, x2, 4096, 1024, 4096, 8);
}

// Round 9
// 251.060 us; speedup vs baseline: 1.6151x; 1.0084x over previous
//
#include <hip/hip_runtime.h>
#include <hip/hip_bf16.h>
#include <math.h>

typedef __bf16 bf16;
typedef __attribute__((ext_vector_type(8))) __bf16 bf16x8;
typedef __attribute__((ext_vector_type(4))) __bf16 bf16x4;
typedef __attribute__((ext_vector_type(4))) float f32x4;

#define DEV static __device__ __forceinline__

typedef const void __attribute__((address_space(1)))* gptr_t;
typedef void __attribute__((address_space(3)))* lptr_t;

DEV void async16(const void* g, void* l) {
  __builtin_amdgcn_global_load_lds((gptr_t)g, (lptr_t)l, 16, 0, 0);
}

DEV void wg_barrier() {
  __builtin_amdgcn_sched_barrier(0);
  __builtin_amdgcn_s_barrier();
  __builtin_amdgcn_sched_barrier(0);
}

// ---------------- fused fp32 -> bf16 convert (4 weight arrays) ----------------
__global__ __launch_bounds__(256) void f2b4_kernel(const float* __restrict__ s0,
                                                   const float* __restrict__ s1,
                                                   const float* __restrict__ s2,
                                                   const float* __restrict__ s3,
                                                   bf16* __restrict__ d0, bf16* __restrict__ d1,
                                                   bf16* __restrict__ d2, bf16* __restrict__ d3,
                                                   int n0, int n1, int n2, int n3) {
  int i = (blockIdx.x * 256 + threadIdx.x) * 4;
  const float* s;
  bf16* d;
  int off;
  if (i < n0) { s = s0; d = d0; off = i; }
  else if (i < n0 + n1) { s = s1; d = d1; off = i - n0; }
  else if (i < n0 + n1 + n2) { s = s2; d = d2; off = i - n0 - n1; }
  else if (i < n0 + n1 + n2 + n3) { s = s3; d = d3; off = i - n0 - n1 - n2; }
  else return;
  float4 v = *(const float4*)(s + off);
  d[off + 0] = (bf16)v.x;
  d[off + 1] = (bf16)v.y;
  d[off + 2] = (bf16)v.z;
  d[off + 3] = (bf16)v.w;
}

// ---------------- LayerNorm: fp32 in -> bf16 out, row = 1024 ----------------
__global__ __launch_bounds__(256) void ln_kernel(const float* __restrict__ in,
                                                 const float* __restrict__ g,
                                                 const float* __restrict__ b,
                                                 bf16* __restrict__ out) {
  const int row = blockIdx.x;
  const int tid = threadIdx.x;
  float4 v = ((const float4*)(in + (size_t)row * 1024))[tid];
  float s = v.x + v.y + v.z + v.w;
  float s2 = v.x * v.x + v.y * v.y + v.z * v.z + v.w * v.w;
#pragma unroll
  for (int off = 1; off < 64; off <<= 1) {
    s += __shfl_xor(s, off);
    s2 += __shfl_xor(s2, off);
  }
  __shared__ float red[8];
  int w = tid >> 6, lane = tid & 63;
  if (lane == 0) { red[w] = s; red[4 + w] = s2; }
  __syncthreads();
  s = red[0] + red[1] + red[2] + red[3];
  s2 = red[4] + red[5] + red[6] + red[7];
  const float mean = s * (1.f / 1024.f);
  const float var = s2 * (1.f / 1024.f) - mean * mean;
  const float rstd = rsqrtf(var + 1e-5f);
  float4 gv = ((const float4*)g)[tid];
  float4 bv = ((const float4*)b)[tid];
  bf16* orow = out + (size_t)row * 1024 + tid * 4;
  orow[0] = (bf16)((v.x - mean) * rstd * gv.x + bv.x);
  orow[1] = (bf16)((v.y - mean) * rstd * gv.y + bv.y);
  orow[2] = (bf16)((v.z - mean) * rstd * gv.z + bv.z);
  orow[3] = (bf16)((v.w - mean) * rstd * gv.w + bv.w);
}

// ---------------- 256x256 deep-pipelined GEMM: C = A * B^T ----------------
// EPI 0: bf16 out. EPI 1: bias + exact GELU -> bf16.
template <int EPI>
__global__ __launch_bounds__(512, 2) void gemm256(const bf16* __restrict__ A,
                                                  const bf16* __restrict__ B,
                                                  bf16* __restrict__ outb,
                                                  const float* __restrict__ bias,
                                                  int M, int N, int K, int gridN) {
  __shared__ bf16 As[2][256 * 64];
  __shared__ bf16 Bs[2][256 * 64];
  const int nwg = gridDim.x;
  const int bid = blockIdx.x;
  const int swz = (bid & 7) * (nwg >> 3) + (bid >> 3);  // nwg % 8 == 0 (bijective)
  const int bx = swz % gridN, by = swz / gridN;
  const int brow = by * 256, bcol = bx * 256;
  const int tid = threadIdx.x;
  const int lane = tid & 63, wid = tid >> 6;
  const int wm = wid >> 2, wn = wid & 3;
  const int lr = lane & 15, lk4 = lane >> 4;
  const int strow = tid >> 3, stc = tid & 7;
  const int NT = K >> 6;
  f32x4 acc[8][4] = {};

#define STAGE(tt, bb)                                                                   \
  {                                                                                     \
    const int k0_ = (tt)*64;                                                            \
    _Pragma("unroll") for (int s_ = 0; s_ < 4; ++s_) {                                  \
      const int r_ = s_ * 64 + strow;                                                   \
      const int g_ = (stc ^ (strow & 7)) * 8;                                           \
      async16(A + (size_t)(brow + r_) * K + k0_ + g_, &As[bb][r_ * 64 + stc * 8]);      \
      async16(B + (size_t)(bcol + r_) * K + k0_ + g_, &Bs[bb][r_ * 64 + stc * 8]);      \
    }                                                                                   \
  }

  STAGE(0, 0);
  STAGE(1, 1);
  asm volatile("s_waitcnt vmcnt(8)" ::: "memory");
  wg_barrier();

  for (int t = 0; t < NT; ++t) {
    const int cur = t & 1;
    bf16x8 af[8][2], bfr[4][2];
#pragma unroll
    for (int m = 0; m < 8; ++m)
#pragma unroll
      for (int kk = 0; kk < 2; ++kk) {
        const int row = wm * 128 + m * 16 + lr;
        const int kc = kk * 4 + lk4;
        af[m][kk] = *(const bf16x8*)&As[cur][row * 64 + ((kc ^ (row & 7)) * 8)];
      }
#pragma unroll
    for (int n = 0; n < 4; ++n)
#pragma unroll
      for (int kk = 0; kk < 2; ++kk) {
        const int row = wn * 64 + n * 16 + lr;
        const int kc = kk * 4 + lk4;
        bfr[n][kk] = *(const bf16x8*)&Bs[cur][row * 64 + ((kc ^ (row & 7)) * 8)];
      }
    asm volatile("s_waitcnt lgkmcnt(0)" ::: "memory");
    wg_barrier();
    if (t + 2 < NT) STAGE(t + 2, cur);
    __builtin_amdgcn_s_setprio(1);
#pragma unroll
    for (int m = 0; m < 8; ++m)
#pragma unroll
      for (int n = 0; n < 4; ++n) {
        acc[m][n] = __builtin_amdgcn_mfma_f32_16x16x32_bf16(af[m][0], bfr[n][0], acc[m][n], 0, 0, 0);
        acc[m][n] = __builtin_amdgcn_mfma_f32_16x16x32_bf16(af[m][1], bfr[n][1], acc[m][n], 0, 0, 0);
      }
    __builtin_amdgcn_s_setprio(0);
    if (t + 1 < NT) {
      if (t + 2 < NT) {
        asm volatile("s_waitcnt vmcnt(8)" ::: "memory");
      } else {
        asm volatile("s_waitcnt vmcnt(0)" ::: "memory");
      }
      wg_barrier();
    }
  }
#undef STAGE
  const int r0 = brow + wm * 128 + lk4 * 4;
  const int c0 = bcol + wn * 64 + lr;
  float bias_v[4];
  if (EPI == 1) {
#pragma unroll
    for (int n = 0; n < 4; ++n) bias_v[n] = bias[c0 + n * 16];
  }
#pragma unroll
  for (int m = 0; m < 8; ++m)
#pragma unroll
    for (int n = 0; n < 4; ++n)
#pragma unroll
      for (int j = 0; j < 4; ++j) {
        const int r = r0 + m * 16 + j;
        const int c = c0 + n * 16;
        float v = acc[m][n][j];
        if (EPI == 1) {
          v += bias_v[n];
          v = 0.5f * v * (1.0f + erff(v * 0.70710678118654752f));
        }
        outb[(size_t)r * N + c] = (bf16)v;
      }
}

// ---------------- 128x128 deep-pipelined GEMM: outf = A*B^T + bias + resid ----------------
__global__ __launch_bounds__(512, 2) void gemm128(const bf16* __restrict__ A,
                                                  const bf16* __restrict__ B,
                                                  float* __restrict__ outf,
                                                  const float* __restrict__ bias,
                                                  const float* __restrict__ resid,
                                                  int M, int N, int K, int gridN) {
  __shared__ bf16 As[2][128 * 64];
  __shared__ bf16 Bs[2][128 * 64];
  const int nwg = gridDim.x;
  const int bid = blockIdx.x;
  const int swz = (bid & 7) * (nwg >> 3) + (bid >> 3);  // nwg % 8 == 0
  const int bx = swz % gridN, by = swz / gridN;
  const int brow = by * 128, bcol = bx * 128;
  const int tid = threadIdx.x;
  const int lane = tid & 63, wid = tid >> 6;
  const int wm = wid >> 2, wn = wid & 3;  // 2 x 4 waves; per-wave 64x32
  const int lr = lane & 15, lk4 = lane >> 4;
  const int strow = tid >> 3, stc = tid & 7;
  const int NT = K >> 6;
  f32x4 acc[4][2] = {};

#define STAGE1(tt, bb)                                                                  \
  {                                                                                     \
    const int k0_ = (tt)*64;                                                            \
    _Pragma("unroll") for (int s_ = 0; s_ < 2; ++s_) {                                  \
      const int r_ = s_ * 64 + strow;                                                   \
      const int g_ = (stc ^ (strow & 7)) * 8;                                           \
      async16(A + (size_t)(brow + r_) * K + k0_ + g_, &As[bb][r_ * 64 + stc * 8]);      \
      async16(B + (size_t)(bcol + r_) * K + k0_ + g_, &Bs[bb][r_ * 64 + stc * 8]);      \
    }                                                                                   \
  }

  STAGE1(0, 0);
  STAGE1(1, 1);
  asm volatile("s_waitcnt vmcnt(4)" ::: "memory");
  wg_barrier();

  for (int t = 0; t < NT; ++t) {
    const int cur = t & 1;
    bf16x8 af[4][2], bfr[2][2];
#pragma unroll
    for (int m = 0; m < 4; ++m)
#pragma unroll
      for (int kk = 0; kk < 2; ++kk) {
        const int row = wm * 64 + m * 16 + lr;
        const int kc = kk * 4 + lk4;
        af[m][kk] = *(const bf16x8*)&As[cur][row * 64 + ((kc ^ (row & 7)) * 8)];
      }
#pragma unroll
    for (int n = 0; n < 2; ++n)
#pragma unroll
      for (int kk = 0; kk < 2; ++kk) {
        const int row = wn * 32 + n * 16 + lr;
        const int kc = kk * 4 + lk4;
        bfr[n][kk] = *(const bf16x8*)&Bs[cur][row * 64 + ((kc ^ (row & 7)) * 8)];
      }
    asm volatile("s_waitcnt lgkmcnt(0)" ::: "memory");
    wg_barrier();
    if (t + 2 < NT) STAGE1(t + 2, cur);
    __builtin_amdgcn_s_setprio(1);
#pragma unroll
    for (int m = 0; m < 4; ++m)
#pragma unroll
      for (int n = 0; n < 2; ++n) {
        acc[m][n] = __builtin_amdgcn_mfma_f32_16x16x32_bf16(af[m][0], bfr[n][0], acc[m][n], 0, 0, 0);
        acc[m][n] = __builtin_amdgcn_mfma_f32_16x16x32_bf16(af[m][1], bfr[n][1], acc[m][n], 0, 0, 0);
      }
    __builtin_amdgcn_s_setprio(0);
    if (t + 1 < NT) {
      if (t + 2 < NT) {
        asm volatile("s_waitcnt vmcnt(4)" ::: "memory");
      } else {
        asm volatile("s_waitcnt vmcnt(0)" ::: "memory");
      }
      wg_barrier();
    }
  }
#undef STAGE1
  const int r0 = brow + wm * 64 + lk4 * 4;
  const int c0 = bcol + wn * 32 + lr;
#pragma unroll
  for (int m = 0; m < 4; ++m)
#pragma unroll
    for (int n = 0; n < 2; ++n)
#pragma unroll
      for (int j = 0; j < 4; ++j) {
        const int r = r0 + m * 16 + j;
        const int c = c0 + n * 16;
        outf[(size_t)r * N + c] = acc[m][n][j] + bias[c] + resid[(size_t)r * N + c];
      }
}

// ---------------- Flash attention (QBLK=128, 8 waves, swapped-operand) ----------------
// LDS padded to 56KB so exactly 2 blocks/CU pack evenly (48KB allowed 3 -> greedy
// packing left ~1/3 of CUs idle). 1-D grid with XCD-chunked swizzle: each XCD
// owns 4 bh's K/V (2MB < 4MB L2).
__global__ __launch_bounds__(512, 4) void flash_kernel(const bf16* __restrict__ qkv,
                                                       bf16* __restrict__ out) {
  const int bid = blockIdx.x;                 // 0..511
  const int swz = (bid & 7) * 64 + (bid >> 3);  // XCD-chunked (512 = 8*64, bijective)
  const int qt = swz & 15;
  const int bh = swz >> 4;
  const int b = bh >> 4, h = bh & 15;
  const int tid = threadIdx.x;
  const int lane = tid & 63, w = tid >> 6;
  const int lr = lane & 15, lk4 = lane >> 4;
  const bf16* Qp = qkv + (size_t)(b * 2048) * 3072 + h * 64;
  const bf16* Kp = Qp + 1024;
  const bf16* Vp = Qp + 2048;
  __shared__ bf16 Ks[2][64 * 64];
  __shared__ bf16 VTs[2][64 * 64];
  __shared__ bf16 Ps[128 * 64 + 4096];  // +8KB pad -> 56KB total LDS
  const int qw0 = qt * 128 + w * 16;
  const float SC = 0.125f * 1.44269504f;   // head-scale * log2(e), applied in fp32
  const float THRU = 8.0f / SC;            // defer-max threshold in raw-score units
  bf16x8 qf[2];
#pragma unroll
  for (int kk = 0; kk < 2; ++kk)
    qf[kk] = *(const bf16x8*)(Qp + (size_t)(qw0 + lr) * 3072 + kk * 32 + lk4 * 8);
  f32x4 o[4] = {};
  float mrun = -1e30f, lrun = 0.f;
  const int sr = tid >> 3, sc8 = tid & 7;          // K staging: row, chunk (512 thr = full tile)
  const int vd = tid & 63, vkc = (tid >> 6) * 8;   // V: d row, 8-kv group
  const int vch = tid >> 6;                        // chunk index 0..7
  const int prow = (w * 16 + lr) * 64;
  bf16 vv[8];
  // ---- prologue: stage tile 0 ----
  async16(Kp + (size_t)sr * 3072 + (sc8 ^ (sr & 7)) * 8, &Ks[0][sr * 64 + sc8 * 8]);
#pragma unroll
  for (int j = 0; j < 8; ++j) vv[j] = Vp[(size_t)(vkc + j) * 3072 + vd];
  {
    bf16x8 a;
#pragma unroll
    for (int j = 0; j < 8; ++j) a[j] = vv[j];
    *(bf16x8*)&VTs[0][vd * 64 + ((vch ^ (vd & 7)) * 8)] = a;
  }
  __syncthreads();
  for (int t = 0; t < 32; ++t) {
    const int cur = t & 1, nxt = cur ^ 1;
    // ---- prefetch next tile (K -> LDS async, V -> regs) ----
    if (t < 31) {
      const size_t kv0n = (size_t)(t + 1) * 64;
      async16(Kp + (kv0n + sr) * 3072 + (sc8 ^ (sr & 7)) * 8, &Ks[nxt][sr * 64 + sc8 * 8]);
#pragma unroll
      for (int j = 0; j < 8; ++j) vv[j] = Vp[(kv0n + vkc + j) * 3072 + vd];
    }
    // ---- S^T = K Q^T (lane: q = lr, kv = n*16 + lk4*4 + j) ----
    f32x4 st[4] = {};
    __builtin_amdgcn_s_setprio(1);
#pragma unroll
    for (int n = 0; n < 4; ++n)
#pragma unroll
      for (int kk = 0; kk < 2; ++kk) {
        bf16x8 kf = *(const bf16x8*)&Ks[cur][(n * 16 + lr) * 64 + (((kk * 4 + lk4) ^ (lr & 7)) * 8)];
        st[n] = __builtin_amdgcn_mfma_f32_16x16x32_bf16(kf, qf[kk], st[n], 0, 0, 0);
      }
    __builtin_amdgcn_s_setprio(0);
    // ---- online softmax (lane-local; 2+2 shfls). m tracked in RAW units. ----
    float m01 = fmaxf(fmaxf(st[0][0], st[0][1]), fmaxf(st[0][2], st[0][3]));
    float m23 = fmaxf(fmaxf(st[1][0], st[1][1]), fmaxf(st[1][2], st[1][3]));
    float m45 = fmaxf(fmaxf(st[2][0], st[2][1]), fmaxf(st[2][2], st[2][3]));
    float m67 = fmaxf(fmaxf(st[3][0], st[3][1]), fmaxf(st[3][2], st[3][3]));
    float mx = fmaxf(fmaxf(m01, m23), fmaxf(m45, m67));
    mx = fmaxf(mx, __shfl_xor(mx, 16));
    mx = fmaxf(mx, __shfl_xor(mx, 32));
    const bool skip = __all(mx <= mrun + THRU);
    const float mn = skip ? mrun : fmaxf(mrun, mx);
    const float mnS = mn * SC;
    float rs = 0.f;
#pragma unroll
    for (int n = 0; n < 4; ++n) {
      float p0 = exp2f(fmaf(st[n][0], SC, -mnS));
      float p1 = exp2f(fmaf(st[n][1], SC, -mnS));
      float p2 = exp2f(fmaf(st[n][2], SC, -mnS));
      float p3 = exp2f(fmaf(st[n][3], SC, -mnS));
      rs += (p0 + p1) + (p2 + p3);
      bf16x4 pk;
      pk[0] = (bf16)p0; pk[1] = (bf16)p1; pk[2] = (bf16)p2; pk[3] = (bf16)p3;
      *(bf16x4*)&Ps[prow + (((n * 2 + (lk4 >> 1)) ^ (lr & 7)) * 8) + (lk4 & 1) * 4] = pk;
    }
    rs += __shfl_xor(rs, 16);
    rs += __shfl_xor(rs, 32);
    if (!skip) {
      const float alpha = exp2f(fmaf(mrun, SC, -mnS));
      lrun = lrun * alpha + rs;
      mrun = mn;
#pragma unroll
      for (int c = 0; c < 4; ++c)
#pragma unroll
        for (int j = 0; j < 4; ++j) o[c][j] *= alpha;
    } else {
      lrun += rs;
    }
    // ---- P^T operand (own wave's rows only) ----
    bf16x8 pb[2];
#pragma unroll
    for (int kk = 0; kk < 2; ++kk)
      pb[kk] = *(const bf16x8*)&Ps[prow + (((kk * 4 + lk4) ^ (lr & 7)) * 8)];
    // ---- O^T += V^T P^T ----
    __builtin_amdgcn_s_setprio(1);
#pragma unroll
    for (int c = 0; c < 4; ++c)
#pragma unroll
      for (int kk = 0; kk < 2; ++kk) {
        bf16x8 vfr = *(const bf16x8*)&VTs[cur][(c * 16 + lr) * 64 + (((kk * 4 + lk4) ^ (lr & 7)) * 8)];
        o[c] = __builtin_amdgcn_mfma_f32_16x16x32_bf16(vfr, pb[kk], o[c], 0, 0, 0);
      }
    __builtin_amdgcn_s_setprio(0);
    // ---- late write of prefetched V^T ----
    if (t < 31) {
      bf16x8 a;
#pragma unroll
      for (int j = 0; j < 8; ++j) a[j] = vv[j];
      *(bf16x8*)&VTs[nxt][vd * 64 + ((vch ^ (vd & 7)) * 8)] = a;
    }
    __syncthreads();
  }
  const float inv = 1.f / lrun;
#pragma unroll
  for (int c = 0; c < 4; ++c) {
    bf16x4 ov;
#pragma unroll
    for (int j = 0; j < 4; ++j) ov[j] = (bf16)(o[c][j] * inv);
    *(bf16x4*)&out[(size_t)(b * 2048 + qw0 + lr) * 1024 + h * 64 + c * 16 + lk4 * 4] = ov;
  }
}

// ---------------- launch ----------------
extern "C" void kernel_launch(void* const* d_in, const int* in_sizes, int n_in,
                              void* d_out, int out_size, void* d_ws, size_t ws_size,
                              hipStream_t stream) {
  const float* x      = (const float*)d_in[0];
  const float* w_qkv  = (const float*)d_in[1];
  const float* w_proj = (const float*)d_in[2];
  const float* b_proj = (const float*)d_in[3];
  const float* ln1_g  = (const float*)d_in[4];
  const float* ln1_b  = (const float*)d_in[5];
  const float* ln2_g  = (const float*)d_in[6];
  const float* ln2_b  = (const float*)d_in[7];
  const float* w_fc1  = (const float*)d_in[8];
  const float* b_fc1  = (const float*)d_in[9];
  const float* w_fc2  = (const float*)d_in[10];
  const float* b_fc2  = (const float*)d_in[11];

  char* W = (char*)d_ws;
  bf16* wqkvb = (bf16*)(W + 0);                    //  6,291,456
  bf16* wprojb = (bf16*)(W + 6291456);             //  2,097,152
  bf16* wfc1b = (bf16*)(W + 8388608);              //  8,388,608
  bf16* wfc2b = (bf16*)(W + 16777216);             //  8,388,608
  bf16* xn    = (bf16*)(W + 25165824);             //  8,388,608
  bf16* qkvb  = (bf16*)(W + 33554432);             // 25,165,824
  bf16* attnb = (bf16*)(W + 58720256);             //  8,388,608
  float* x2   = (float*)(W + 67108864);            // 16,777,216
  bf16* hbuf  = (bf16*)(W + 83886080);             // 33,554,432
  float* outf = (float*)d_out;

  f2b4_kernel<<<12288, 256, 0, stream>>>(w_qkv, w_proj, w_fc1, w_fc2,
                                         wqkvb, wprojb, wfc1b, wfc2b,
                                         3145728, 1048576, 4194304, 4194304);

  // LN1
  ln_kernel<<<4096, 256, 0, stream>>>(x, ln1_g, ln1_b, xn);
  // QKV GEMM (256² deep-pipeline, grid 12x16=192)
  gemm256<0><<<192, 512, 0, stream>>>(xn, wqkvb, qkvb, nullptr, 4096, 3072, 1024, 12);
  // attention (QBLK=128, 8 waves, XCD-chunked 1-D grid)
  flash_kernel<<<512, 512, 0, stream>>>(qkvb, attnb);
  // proj + bias + residual -> x2 (128² deep-pipeline, grid 32x8=256)
  gemm128<<<256, 512, 0, stream>>>(attnb, wprojb, x2, b_proj, x, 4096, 1024, 1024, 8);
  // LN2
  ln_kernel<<<4096, 256, 0, stream>>>(x2, ln2_g, ln2_b, xn);
  // FC1 + bias + GELU (256² deep-pipeline, grid 16x16=256)
  gemm256<1><<<256, 512, 0, stream>>>(xn, wfc1b, hbuf, b_fc1, 4096, 4096, 1024, 16);
  // FC2 + bias + residual -> out (128² deep-pipeline, grid 32x8=256)
  gemm128<<<256, 512, 0, stream>>>(hbuf, wfc2b, outf, b_fc2, x2, 4096, 1024, 4096, 8);
}